// Round 6
// baseline (596.698 us; speedup 1.0000x reference)
//
#include <hip/hip_runtime.h>
#include <cstddef>

// Problem constants
#define NB 128    // B
#define NT 64     // N0 (time/positions)
#define ND 32     // D0 == D1
#define NG 64     // N1 (groups/capsules)
#define NC 2048   // N1*D1 channels
#define KW 65     // conv kernel size
#define EPSZ 1.1920928955078125e-07f

// ws layout (floats)
#define OFF_URAW 0ull
#define SZ_URAW  (3ull * NB * NT * NC)
#define OFF_F    (OFF_URAW + SZ_URAW)
#define SZ_F     (3ull * NB * NC)
#define OFF_S1   (OFF_F + SZ_F)
#define SZ_S1    ((unsigned long long)NB * NT)
#define OFF_KV   (OFF_S1 + SZ_S1)
#define SZ_KV    ((unsigned long long)NB * NT * NT)
// overlays:
//   pre[b][ch][jj]  -> u2 region (dead after k_kv)
//   cwt[o][ci*64+jj]-> u3 region (dead after k_kv)
//   ysum[b][o]      -> u1 region start (dead after k_pre), zeroed after k_pre

__device__ __forceinline__ float foc(float v, float fv) {
  float u = (fmaxf(v, 0.f) + 1e-6f) * 0.2f;
  return u * u * u * fv;
}

// ---------------------------------------------------------------------------
// K1: transform. For each j (0..63) a GEMM  [384 rows=(inp,b)] x [32 i] x [2048 c]
// writes u_raw[inp][b][t=j][ch=c]
// ---------------------------------------------------------------------------
__global__ __launch_bounds__(256) void k_transform(
    const float* __restrict__ x1, const float* __restrict__ x2,
    const float* __restrict__ x3, const float* __restrict__ W,
    float* __restrict__ uraw) {
  int bid = blockIdx.x;
  int j   = bid & 63;
  int nt  = (bid >> 6) & 15;
  int inp = bid >> 10;
  const float* x = (inp == 0) ? x1 : ((inp == 1) ? x2 : x3);
  float* uout = uraw + (size_t)inp * ((size_t)NB * NT * NC);

  __shared__ float as[32][132];  // [i][b]
  __shared__ float bs[32][132];  // [i][c_local]
  int tid = threadIdx.x;

  { // A tile: x[b][j][i]  -> as[i][b]
    int b = tid >> 1, h = tid & 1;
    const float* xp = x + ((size_t)b * NT + j) * ND + h * 16;
#pragma unroll
    for (int q = 0; q < 4; ++q) {
      float4 v = *reinterpret_cast<const float4*>(xp + q * 4);
      int i0 = h * 16 + q * 4;
      as[i0 + 0][b] = v.x; as[i0 + 1][b] = v.y;
      as[i0 + 2][b] = v.z; as[i0 + 3][b] = v.w;
    }
  }
  { // B tile: W[k0+kk][j][i][z] -> bs[i][kk*32+z]
    int kk = tid >> 6, u = tid & 63;
    int i = u >> 1, h = u & 1;
    const float* wp = W + (((size_t)(nt * 4 + kk) * NT + j) * ND + i) * ND + h * 16;
#pragma unroll
    for (int q = 0; q < 4; ++q) {
      float4 v = *reinterpret_cast<const float4*>(wp + q * 4);
      int c0 = kk * 32 + h * 16 + q * 4;
      bs[i][c0 + 0] = v.x; bs[i][c0 + 1] = v.y;
      bs[i][c0 + 2] = v.z; bs[i][c0 + 3] = v.w;
    }
  }
  __syncthreads();

  int tm = tid & 15, tn = tid >> 4;
  int m0 = tm * 8, n0 = tn * 8;
  float acc[8][8];
#pragma unroll
  for (int a = 0; a < 8; ++a)
#pragma unroll
    for (int c = 0; c < 8; ++c) acc[a][c] = 0.f;

#pragma unroll 4
  for (int kk = 0; kk < 32; ++kk) {
    float4 a0 = *reinterpret_cast<const float4*>(&as[kk][m0]);
    float4 a1 = *reinterpret_cast<const float4*>(&as[kk][m0 + 4]);
    float4 b0 = *reinterpret_cast<const float4*>(&bs[kk][n0]);
    float4 b1 = *reinterpret_cast<const float4*>(&bs[kk][n0 + 4]);
    float av[8] = {a0.x, a0.y, a0.z, a0.w, a1.x, a1.y, a1.z, a1.w};
    float bv[8] = {b0.x, b0.y, b0.z, b0.w, b1.x, b1.y, b1.z, b1.w};
#pragma unroll
    for (int mi = 0; mi < 8; ++mi)
#pragma unroll
      for (int ni = 0; ni < 8; ++ni)
        acc[mi][ni] = fmaf(av[mi], bv[ni], acc[mi][ni]);
  }

#pragma unroll
  for (int mi = 0; mi < 8; ++mi) {
    float* cp = uout + ((size_t)(m0 + mi) * NT + j) * NC + nt * 128 + n0;
    float4 v0 = {acc[mi][0], acc[mi][1], acc[mi][2], acc[mi][3]};
    float4 v1 = {acc[mi][4], acc[mi][5], acc[mi][6], acc[mi][7]};
    *reinterpret_cast<float4*>(cp)     = v0;
    *reinterpret_cast<float4*>(cp + 4) = v1;
  }
}

// ---------------------------------------------------------------------------
// K2: focus factors f = sqrt(sum u'^2)/sqrt(sum u'^6), 2 ch per thread.
// For inp==0 also computes s1[b][t] = sum_ch u1'^3 * f (focused row sums).
// grid: inp(3) x b(128) x quarter(4) = 1536 blocks, 256 threads
// ---------------------------------------------------------------------------
__global__ __launch_bounds__(256) void k_factors(
    const float* __restrict__ uraw, float* __restrict__ f,
    float* __restrict__ s1) {
  int bid = blockIdx.x;
  int q = bid & 3, b = (bid >> 2) & 127, inp = bid >> 9;
  const float* u = uraw + ((size_t)inp * NB + b) * ((size_t)NT * NC);
  int tid = threadIdx.x;
  int ch = q * 512 + tid * 2;

  float s2a = 0.f, s6a = 0.f, s2b = 0.f, s6b = 0.f;
  for (int t = 0; t < NT; ++t) {
    float2 v = *reinterpret_cast<const float2*>(u + (size_t)t * NC + ch);
    float ua = (fmaxf(v.x, 0.f) + 1e-6f) * 0.2f;
    float p2a = ua * ua, p3a = p2a * ua;
    s2a += p2a; s6a += p3a * p3a;
    float ub = (fmaxf(v.y, 0.f) + 1e-6f) * 0.2f;
    float p2b = ub * ub, p3b = p2b * ub;
    s2b += p2b; s6b += p3b * p3b;
  }
  float fa = sqrtf(s2a) / sqrtf(s6a);
  float fb = sqrtf(s2b) / sqrtf(s6b);
  float2 fv = {fa, fb};
  *reinterpret_cast<float2*>(f + ((size_t)inp * NB + b) * NC + ch) = fv;

  if (inp == 0) {
    __shared__ float part[NT][4];
    int wid = tid >> 6, lane = tid & 63;
    for (int t = 0; t < NT; ++t) {
      float2 v = *reinterpret_cast<const float2*>(u + (size_t)t * NC + ch);
      float ua = (fmaxf(v.x, 0.f) + 1e-6f) * 0.2f;
      float ub = (fmaxf(v.y, 0.f) + 1e-6f) * 0.2f;
      float val = ua * ua * ua * fa + ub * ub * ub * fb;
#pragma unroll
      for (int m = 32; m >= 1; m >>= 1) val += __shfl_xor(val, m, 64);
      if (lane == 0) part[t][wid] = val;
    }
    __syncthreads();
    if (tid < NT)
      atomicAdd(&s1[b * NT + tid],
                part[tid][0] + part[tid][1] + part[tid][2] + part[tid][3]);
  }
}

// ---------------------------------------------------------------------------
// K3: zero accumulators
// ---------------------------------------------------------------------------
__global__ void k_zero(float* __restrict__ p, int n) {
  int i = blockIdx.x * blockDim.x + threadIdx.x;
  int stride = gridDim.x * blockDim.x;
  for (; i < n; i += stride) p[i] = 0.f;
}

// ---------------------------------------------------------------------------
// K4: kv[b][t1][t2] = sum_ch u2'[ch][t1]*u3'[ch][t2]  (focused).
// Gram-of-rows formulation in NATIVE [t][ch] layout: kv[t1][t2] =
// dot(u2'row_t1, u3'row_t2).  One WAVE computes the full 64x64 tile with an
// 8x8 per-lane register tile: per ch-pair 16 ds_read_b64 feed 128 FMAs
// (1 B/FMA -> VALU-bound).  No transpose staging; focus applied once during
// stage and shared via LDS broadcast.  4 waves/block cover 256 ch (64 each,
// 4 chunks of 16); pairwise LDS reduction then atomics (2 tiles/block).
// grid: b(128) x ks(8) = 1024 blocks, 256 threads.
// ---------------------------------------------------------------------------
__global__ __launch_bounds__(256) void k_kv(
    const float* __restrict__ uraw, const float* __restrict__ f,
    float* __restrict__ kv) {
  int b = blockIdx.x >> 3, ks = blockIdx.x & 7;
  int wv = threadIdx.x >> 6, lane = threadIdx.x & 63;
  const float* u2 = uraw + ((size_t)NB + b) * ((size_t)NT * NC);
  const float* u3 = uraw + (2ull * NB + b) * ((size_t)NT * NC);
  const float* f2 = f + ((size_t)NB + b) * NC;
  const float* f3 = f + (2ull * NB + b) * NC;

  // per-wave staging: [wave][op][t][ch16 + 2pad]; 9216 floats total, also
  // reused as the 2x(64x66) exchange buffer in the epilogue.
  __shared__ float sbuf[4][2][64][18];

  int tm = lane >> 3, tn = lane & 7;   // 8x8 lane grid over the 64x64 tile
  int tq = lane >> 2, q = lane & 3;    // staging map: 16 t x 4 ch-quads

  float acc[8][8];
#pragma unroll
  for (int i = 0; i < 8; ++i)
#pragma unroll
    for (int j = 0; j < 8; ++j) acc[i][j] = 0.f;

  for (int chunk = 0; chunk < 4; ++chunk) {
    int ch0 = ks * 256 + wv * 64 + chunk * 16;
    float4 f2q = *reinterpret_cast<const float4*>(f2 + ch0 + q * 4);
    float4 f3q = *reinterpret_cast<const float4*>(f3 + ch0 + q * 4);
    __syncthreads();
#pragma unroll
    for (int p = 0; p < 4; ++p) {
      int t = p * 16 + tq;
      float4 v2 = *reinterpret_cast<const float4*>(u2 + (size_t)t * NC + ch0 + q * 4);
      float4 v3 = *reinterpret_cast<const float4*>(u3 + (size_t)t * NC + ch0 + q * 4);
      float* w2 = &sbuf[wv][0][t][q * 4];
      float* w3 = &sbuf[wv][1][t][q * 4];
      float2 a0 = {foc(v2.x, f2q.x), foc(v2.y, f2q.y)};
      float2 a1 = {foc(v2.z, f2q.z), foc(v2.w, f2q.w)};
      float2 c0 = {foc(v3.x, f3q.x), foc(v3.y, f3q.y)};
      float2 c1 = {foc(v3.z, f3q.z), foc(v3.w, f3q.w)};
      *reinterpret_cast<float2*>(w2)     = a0;
      *reinterpret_cast<float2*>(w2 + 2) = a1;
      *reinterpret_cast<float2*>(w3)     = c0;
      *reinterpret_cast<float2*>(w3 + 2) = c1;
    }
    __syncthreads();

#pragma unroll
    for (int k = 0; k < 8; ++k) {     // 8 ch-pairs per chunk
      float2 af[8], bf[8];
#pragma unroll
      for (int i = 0; i < 8; ++i)
        af[i] = *reinterpret_cast<const float2*>(&sbuf[wv][0][tm * 8 + i][k * 2]);
#pragma unroll
      for (int j = 0; j < 8; ++j)
        bf[j] = *reinterpret_cast<const float2*>(&sbuf[wv][1][tn * 8 + j][k * 2]);
#pragma unroll
      for (int i = 0; i < 8; ++i)
#pragma unroll
        for (int j = 0; j < 8; ++j)
          acc[i][j] = fmaf(af[i].y, bf[j].y, fmaf(af[i].x, bf[j].x, acc[i][j]));
    }
  }

  // pairwise reduce (waves 0->1, 2->3) then atomics: halves atomic traffic
  float* xch = &sbuf[0][0][0][0];
  float* tile = xch + (wv >> 1) * (64 * 66);
  __syncthreads();
  if ((wv & 1) == 0) {
#pragma unroll
    for (int i = 0; i < 8; ++i)
#pragma unroll
      for (int j = 0; j < 8; ++j)
        tile[(tm * 8 + i) * 66 + tn * 8 + j] = acc[i][j];
  }
  __syncthreads();
  if (wv & 1) {
    float* kvp = kv + (size_t)b * (NT * NT);
#pragma unroll
    for (int i = 0; i < 8; ++i)
#pragma unroll
      for (int j = 0; j < 8; ++j)
        atomicAdd(&kvp[(tm * 8 + i) * 64 + tn * 8 + j],
                  acc[i][j] + tile[(tm * 8 + i) * 66 + tn * 8 + j]);
  }
}

// ---------------------------------------------------------------------------
// K5: conv-weight transform (prefix-sum domain).
// ---------------------------------------------------------------------------
__global__ __launch_bounds__(64) void k_cwt(
    const float* __restrict__ cw, float* __restrict__ cwt) {
  int o = blockIdx.x;
  int tid = threadIdx.x;
  __shared__ float row[32 * KW];
  for (int i = tid; i < 32 * KW; i += 64) row[i] = cw[(size_t)o * (32 * KW) + i];
  __syncthreads();
  int jj = tid, j = jj + 1;
  for (int ci = 0; ci < 32; ++ci) {
    float v = 0.f;
    if (j <= 32) v -= row[ci * KW + j + 32];
    if (j >= 32 && j <= 63) v += row[ci * KW + j - 32];
    if (j == 64) {
      float s = 0.f;
      for (int k = 32; k <= 64; ++k) s += row[ci * KW + k];
      v += s;
    }
    cwt[(size_t)o * 2048 + ci * 64 + jj] = v;
  }
}

// ---------------------------------------------------------------------------
// K6: pre[b][ch][jj] = z[b,ch] * sum_t1 ut[t1,ch] * kvpre[t1][jj]
// grid: b(128) x ch8(8) = 1024 blocks (256 ch each), 256 threads
// ---------------------------------------------------------------------------
__global__ __launch_bounds__(256) void k_pre(
    const float* __restrict__ uraw, const float* __restrict__ f,
    const float* __restrict__ kvg, const float* __restrict__ s1g,
    float* __restrict__ pre) {
  int b = blockIdx.x >> 3, q = blockIdx.x & 7;
  int chbase = q * 256;
  const float* u1 = uraw + (size_t)b * ((size_t)NT * NC);
  const float* f1 = f + (size_t)b * NC;
  int tid = threadIdx.x;

  __shared__ float kvpreL[64][68];
  __shared__ float s1L[64];
  __shared__ float utL[64][132];   // [t][c4-skewed ch_local], skew c4*33

#pragma unroll
  for (int qq = 0; qq < 16; ++qq) {
    int i = tid + qq * 256;
    kvpreL[i >> 6][i & 63] = kvg[(size_t)b * (NT * NT) + i];
  }
  if (tid < 64) s1L[tid] = s1g[b * NT + tid];
  __syncthreads();
  if (tid < 64) {
    float run = 0.f;
    for (int t2 = 0; t2 < 64; ++t2) {
      run += kvpreL[tid][t2];
      kvpreL[tid][t2] = run;
    }
  }

  int cg = tid >> 3, tg = tid & 7;   // cg: 4-ch group, tg: 8-j group
  for (int tile = 0; tile < 2; ++tile) {
    int ch0 = chbase + tile * 128;
    __syncthreads();
    { // stage focused u1: utL[t][c4*33 + w] = u1'[b][ch0 + c4*32 + w][t]
      int t = tid >> 2, c4 = tid & 3;
      const float* up = u1 + (size_t)t * NC + ch0 + c4 * 32;
      const float* fp = f1 + ch0 + c4 * 32;
#pragma unroll
      for (int qq = 0; qq < 8; ++qq) {
        float4 v  = *reinterpret_cast<const float4*>(up + qq * 4);
        float4 fv = *reinterpret_cast<const float4*>(fp + qq * 4);
        float vv[4] = {v.x, v.y, v.z, v.w};
        float ff[4] = {fv.x, fv.y, fv.z, fv.w};
#pragma unroll
        for (int r = 0; r < 4; ++r) {
          float uu = (fmaxf(vv[r], 0.f) + 1e-6f) * 0.2f;
          utL[t][c4 * 33 + qq * 4 + r] = uu * uu * uu * ff[r];
        }
      }
    }
    __syncthreads();

    int cl = cg * 4;
    int sk = (cl >> 5) * 33 + (cl & 31);
    float acc[4][8];
#pragma unroll
    for (int r = 0; r < 4; ++r)
#pragma unroll
      for (int c = 0; c < 8; ++c) acc[r][c] = 0.f;
    float accz[4] = {0.f, 0.f, 0.f, 0.f};

#pragma unroll 4
    for (int t1 = 0; t1 < 64; ++t1) {
      float4 a = *reinterpret_cast<const float4*>(&utL[t1][sk]);
      float s = s1L[t1];
      float4 k0 = *reinterpret_cast<const float4*>(&kvpreL[t1][tg * 8]);
      float4 k1 = *reinterpret_cast<const float4*>(&kvpreL[t1][tg * 8 + 4]);
      float aa[4] = {a.x, a.y, a.z, a.w};
      float kk[8] = {k0.x, k0.y, k0.z, k0.w, k1.x, k1.y, k1.z, k1.w};
#pragma unroll
      for (int r = 0; r < 4; ++r) {
        accz[r] = fmaf(aa[r], s, accz[r]);
#pragma unroll
        for (int c = 0; c < 8; ++c)
          acc[r][c] = fmaf(aa[r], kk[c], acc[r][c]);
      }
    }
#pragma unroll
    for (int r = 0; r < 4; ++r) {
      float z = 1.f / (accz[r] + EPSZ);
      float* pp = pre + ((size_t)b * NC + ch0 + cl + r) * 64 + tg * 8;
      float4 o0 = {acc[r][0] * z, acc[r][1] * z, acc[r][2] * z, acc[r][3] * z};
      float4 o1 = {acc[r][4] * z, acc[r][5] * z, acc[r][6] * z, acc[r][7] * z};
      *reinterpret_cast<float4*>(pp)     = o0;
      *reinterpret_cast<float4*>(pp + 4) = o1;
    }
  }
}

// ---------------------------------------------------------------------------
// K7: GEMM partials  ysum[b][o] += sum_{K-chunk} cwt[o][K] * pre[b][K]
// grid: g(64) x ks(8) = 512 blocks; block = full 128b x 32o, K=256 (4 ci).
// ---------------------------------------------------------------------------
__global__ __launch_bounds__(256) void k_gemm(
    const float* __restrict__ pre, const float* __restrict__ cwt,
    float* __restrict__ ysum) {
  int g = blockIdx.x >> 3, ks = blockIdx.x & 7;
  int tid = threadIdx.x;
  int oh = tid & 7, bh = tid >> 3;   // o = oh*4+j, b = bh*4+i

  __shared__ float AsT[64][132];  // [jj][b]
  __shared__ float BsT[64][36];   // [jj][o]

  float acc[4][4];
#pragma unroll
  for (int i = 0; i < 4; ++i)
#pragma unroll
    for (int j = 0; j < 4; ++j) acc[i][j] = 0.f;

  for (int kc = 0; kc < 4; ++kc) {
    int ci = ks * 4 + kc;           // capsule-relative input channel
    __syncthreads();
    { // stage A transposed: AsT[jj][b] = pre[b][g*32+ci][jj]
      int bb = tid >> 1, jh = (tid & 1) * 32;
      const float* ap = pre + ((size_t)bb * NC + g * 32 + ci) * 64 + jh;
#pragma unroll
      for (int qq = 0; qq < 8; ++qq) {
        float4 v = *reinterpret_cast<const float4*>(ap + qq * 4);
        int jj = jh + qq * 4;
        AsT[jj + 0][bb] = v.x; AsT[jj + 1][bb] = v.y;
        AsT[jj + 2][bb] = v.z; AsT[jj + 3][bb] = v.w;
      }
    }
    if (tid < 128) { // stage B transposed: BsT[jj][o] = cwt[g*32+o][ci*64+jj]
      int o = tid >> 2, jh = (tid & 3) * 16;
      const float* bp = cwt + (size_t)(g * 32 + o) * 2048 + ci * 64 + jh;
#pragma unroll
      for (int qq = 0; qq < 4; ++qq) {
        float4 v = *reinterpret_cast<const float4*>(bp + qq * 4);
        int jj = jh + qq * 4;
        BsT[jj + 0][o] = v.x; BsT[jj + 1][o] = v.y;
        BsT[jj + 2][o] = v.z; BsT[jj + 3][o] = v.w;
      }
    }
    __syncthreads();

#pragma unroll 8
    for (int jj = 0; jj < 64; ++jj) {
      float4 a = *reinterpret_cast<const float4*>(&AsT[jj][bh * 4]);
      float4 bv = *reinterpret_cast<const float4*>(&BsT[jj][oh * 4]);
      float aa[4] = {a.x, a.y, a.z, a.w};
      float bb[4] = {bv.x, bv.y, bv.z, bv.w};
#pragma unroll
      for (int i = 0; i < 4; ++i)
#pragma unroll
        for (int j = 0; j < 4; ++j)
          acc[i][j] = fmaf(aa[i], bb[j], acc[i][j]);
    }
  }

#pragma unroll
  for (int i = 0; i < 4; ++i)
#pragma unroll
    for (int j = 0; j < 4; ++j)
      atomicAdd(&ysum[(size_t)(bh * 4 + i) * NC + g * 32 + oh * 4 + j],
                acc[i][j]);
}

// ---------------------------------------------------------------------------
// K8: epilogue: val = ysum + xsum(pre[..][63]) + 64*bias; squash over 32-group
// grid: b(128) x gq(8) = 1024 blocks, 256 threads = 8 g x 32 o
// ---------------------------------------------------------------------------
__global__ __launch_bounds__(256) void k_out(
    const float* __restrict__ pre, const float* __restrict__ ysum,
    const float* __restrict__ cb, float* __restrict__ out) {
  int tid = threadIdx.x;
  int b = blockIdx.x >> 3;
  int g = (blockIdx.x & 7) * 8 + (tid >> 5);
  int o = tid & 31;
  int go = g * 32 + o;
  float xs = pre[((size_t)b * NC + go) * 64 + 63];
  float val = ysum[(size_t)b * NC + go] + xs + 64.f * cb[go];
  float sq = val * val;
#pragma unroll
  for (int m = 16; m >= 1; m >>= 1) sq += __shfl_xor(sq, m, 32);
  float norm = sqrtf(sq);
  float coef = 1.f - 1.f / (expf(norm) + 1e-20f);
  out[((size_t)b * NG + g) * ND + o] = coef * val / (norm + 1e-20f);
}

// ---------------------------------------------------------------------------
extern "C" void kernel_launch(void* const* d_in, const int* in_sizes, int n_in,
                              void* d_out, int out_size, void* d_ws, size_t ws_size,
                              hipStream_t stream) {
  const float* x1 = (const float*)d_in[0];
  const float* x2 = (const float*)d_in[1];
  const float* x3 = (const float*)d_in[2];
  const float* W  = (const float*)d_in[3];
  const float* cw = (const float*)d_in[4];
  const float* cb = (const float*)d_in[5];
  float* out = (float*)d_out;

  float* ws   = (float*)d_ws;
  float* uraw = ws + OFF_URAW;
  float* f    = ws + OFF_F;
  float* s1   = ws + OFF_S1;
  float* kv   = ws + OFF_KV;
  // overlays:
  float* pre  = uraw + (size_t)NB * NT * NC;        // u2 region
  float* cwt  = uraw + 2ull * NB * NT * NC;         // u3 region
  float* ysum = uraw;                               // u1 region (dead after k_pre)

  k_transform<<<3072, 256, 0, stream>>>(x1, x2, x3, W, uraw);
  k_zero<<<256, 256, 0, stream>>>(s1, (int)(SZ_S1 + SZ_KV));
  k_factors<<<1536, 256, 0, stream>>>(uraw, f, s1);
  k_kv<<<1024, 256, 0, stream>>>(uraw, f, kv);
  k_cwt<<<2048, 64, 0, stream>>>(cw, cwt);
  k_pre<<<1024, 256, 0, stream>>>(uraw, f, kv, s1, pre);
  k_zero<<<256, 256, 0, stream>>>(ysum, (int)(NB * NC));
  k_gemm<<<512, 256, 0, stream>>>(pre, cwt, ysum);
  k_out<<<1024, 256, 0, stream>>>(pre, ysum, cb, out);
}

// Round 7
// 422.892 us; speedup vs baseline: 1.4110x; 1.4110x over previous
//
#include <hip/hip_runtime.h>
#include <cstddef>

// Problem constants
#define NB 128    // B
#define NT 64     // N0 (time/positions)
#define ND 32     // D0 == D1
#define NG 64     // N1 (groups/capsules)
#define NC 2048   // N1*D1 channels
#define KW 65     // conv kernel size
#define EPSZ 1.1920928955078125e-07f

// ws layout (floats)
#define OFF_URAW 0ull
#define SZ_URAW  (3ull * NB * NT * NC)
#define OFF_F    (OFF_URAW + SZ_URAW)
#define SZ_F     (3ull * NB * NC)
#define OFF_S1   (OFF_F + SZ_F)
#define SZ_S1    ((unsigned long long)NB * NT)
#define OFF_KV   (OFF_S1 + SZ_S1)
#define SZ_KV    ((unsigned long long)NB * NT * NT)
// overlays:
//   pre[b][ch][jj]  -> u2 region (dead after k_kv)
//   cwt[o][ci*64+jj]-> u3 region (dead after k_kv)

__device__ __forceinline__ float foc(float v, float fv) {
  float u = (fmaxf(v, 0.f) + 1e-6f) * 0.2f;
  return u * u * u * fv;
}

// ---------------------------------------------------------------------------
// K1: transform. For each j (0..63) a GEMM  [384 rows=(inp,b)] x [32 i] x [2048 c]
// writes u_raw[inp][b][t=j][ch=c]
// ---------------------------------------------------------------------------
__global__ __launch_bounds__(256) void k_transform(
    const float* __restrict__ x1, const float* __restrict__ x2,
    const float* __restrict__ x3, const float* __restrict__ W,
    float* __restrict__ uraw) {
  int bid = blockIdx.x;
  int j   = bid & 63;
  int nt  = (bid >> 6) & 15;
  int inp = bid >> 10;
  const float* x = (inp == 0) ? x1 : ((inp == 1) ? x2 : x3);
  float* uout = uraw + (size_t)inp * ((size_t)NB * NT * NC);

  __shared__ float as[32][132];  // [i][b]
  __shared__ float bs[32][132];  // [i][c_local]
  int tid = threadIdx.x;

  { // A tile: x[b][j][i]  -> as[i][b]
    int b = tid >> 1, h = tid & 1;
    const float* xp = x + ((size_t)b * NT + j) * ND + h * 16;
#pragma unroll
    for (int q = 0; q < 4; ++q) {
      float4 v = *reinterpret_cast<const float4*>(xp + q * 4);
      int i0 = h * 16 + q * 4;
      as[i0 + 0][b] = v.x; as[i0 + 1][b] = v.y;
      as[i0 + 2][b] = v.z; as[i0 + 3][b] = v.w;
    }
  }
  { // B tile: W[k0+kk][j][i][z] -> bs[i][kk*32+z]
    int kk = tid >> 6, u = tid & 63;
    int i = u >> 1, h = u & 1;
    const float* wp = W + (((size_t)(nt * 4 + kk) * NT + j) * ND + i) * ND + h * 16;
#pragma unroll
    for (int q = 0; q < 4; ++q) {
      float4 v = *reinterpret_cast<const float4*>(wp + q * 4);
      int c0 = kk * 32 + h * 16 + q * 4;
      bs[i][c0 + 0] = v.x; bs[i][c0 + 1] = v.y;
      bs[i][c0 + 2] = v.z; bs[i][c0 + 3] = v.w;
    }
  }
  __syncthreads();

  int tm = tid & 15, tn = tid >> 4;
  int m0 = tm * 8, n0 = tn * 8;
  float acc[8][8];
#pragma unroll
  for (int a = 0; a < 8; ++a)
#pragma unroll
    for (int c = 0; c < 8; ++c) acc[a][c] = 0.f;

#pragma unroll 4
  for (int kk = 0; kk < 32; ++kk) {
    float4 a0 = *reinterpret_cast<const float4*>(&as[kk][m0]);
    float4 a1 = *reinterpret_cast<const float4*>(&as[kk][m0 + 4]);
    float4 b0 = *reinterpret_cast<const float4*>(&bs[kk][n0]);
    float4 b1 = *reinterpret_cast<const float4*>(&bs[kk][n0 + 4]);
    float av[8] = {a0.x, a0.y, a0.z, a0.w, a1.x, a1.y, a1.z, a1.w};
    float bv[8] = {b0.x, b0.y, b0.z, b0.w, b1.x, b1.y, b1.z, b1.w};
#pragma unroll
    for (int mi = 0; mi < 8; ++mi)
#pragma unroll
      for (int ni = 0; ni < 8; ++ni)
        acc[mi][ni] = fmaf(av[mi], bv[ni], acc[mi][ni]);
  }

#pragma unroll
  for (int mi = 0; mi < 8; ++mi) {
    float* cp = uout + ((size_t)(m0 + mi) * NT + j) * NC + nt * 128 + n0;
    float4 v0 = {acc[mi][0], acc[mi][1], acc[mi][2], acc[mi][3]};
    float4 v1 = {acc[mi][4], acc[mi][5], acc[mi][6], acc[mi][7]};
    *reinterpret_cast<float4*>(cp)     = v0;
    *reinterpret_cast<float4*>(cp + 4) = v1;
  }
}

// ---------------------------------------------------------------------------
// K2: focus factors f = sqrt(sum u'^2)/sqrt(sum u'^6), 2 ch per thread.
// For inp==0 also computes s1[b][t] = sum_ch u1'^3 * f (focused row sums).
// grid: inp(3) x b(128) x quarter(4) = 1536 blocks, 256 threads
// ---------------------------------------------------------------------------
__global__ __launch_bounds__(256) void k_factors(
    const float* __restrict__ uraw, float* __restrict__ f,
    float* __restrict__ s1) {
  int bid = blockIdx.x;
  int q = bid & 3, b = (bid >> 2) & 127, inp = bid >> 9;
  const float* u = uraw + ((size_t)inp * NB + b) * ((size_t)NT * NC);
  int tid = threadIdx.x;
  int ch = q * 512 + tid * 2;

  float s2a = 0.f, s6a = 0.f, s2b = 0.f, s6b = 0.f;
  for (int t = 0; t < NT; ++t) {
    float2 v = *reinterpret_cast<const float2*>(u + (size_t)t * NC + ch);
    float ua = (fmaxf(v.x, 0.f) + 1e-6f) * 0.2f;
    float p2a = ua * ua, p3a = p2a * ua;
    s2a += p2a; s6a += p3a * p3a;
    float ub = (fmaxf(v.y, 0.f) + 1e-6f) * 0.2f;
    float p2b = ub * ub, p3b = p2b * ub;
    s2b += p2b; s6b += p3b * p3b;
  }
  float fa = sqrtf(s2a) / sqrtf(s6a);
  float fb = sqrtf(s2b) / sqrtf(s6b);
  float2 fv = {fa, fb};
  *reinterpret_cast<float2*>(f + ((size_t)inp * NB + b) * NC + ch) = fv;

  if (inp == 0) {
    __shared__ float part[NT][4];
    int wid = tid >> 6, lane = tid & 63;
    for (int t = 0; t < NT; ++t) {
      float2 v = *reinterpret_cast<const float2*>(u + (size_t)t * NC + ch);
      float ua = (fmaxf(v.x, 0.f) + 1e-6f) * 0.2f;
      float ub = (fmaxf(v.y, 0.f) + 1e-6f) * 0.2f;
      float val = ua * ua * ua * fa + ub * ub * ub * fb;
#pragma unroll
      for (int m = 32; m >= 1; m >>= 1) val += __shfl_xor(val, m, 64);
      if (lane == 0) part[t][wid] = val;
    }
    __syncthreads();
    if (tid < NT)
      atomicAdd(&s1[b * NT + tid],
                part[tid][0] + part[tid][1] + part[tid][2] + part[tid][3]);
  }
}

// ---------------------------------------------------------------------------
// K3: zero accumulators
// ---------------------------------------------------------------------------
__global__ void k_zero(float* __restrict__ p, int n) {
  int i = blockIdx.x * blockDim.x + threadIdx.x;
  int stride = gridDim.x * blockDim.x;
  for (; i < n; i += stride) p[i] = 0.f;
}

// ---------------------------------------------------------------------------
// K4 v3: kv[b][t1][t2] = sum_ch u2'[ch][t1]*u3'[ch][t2]  (focused).
// One WAVE owns the full 64x64 t-tile over its 128-ch slice (4 chunks of 32):
// native [t][ch32] LDS staging (full 128B row segments -> zero overfetch),
// XOR-swizzled columns (q4 ^ (t&7) ^ (t>>3)) -> conflict-free b64 reads,
// 8x8 per-lane register tile, 1 B/FMA.  Per-wave-private LDS: no barriers in
// the main loop.  Cross-wave reduce via LDS dump, wave0 atomics.
// grid: b(128) x ks(4) = 512 blocks, 256 threads (4 waves).
// ---------------------------------------------------------------------------
__global__ __launch_bounds__(256) void k_kv(
    const float* __restrict__ uraw, const float* __restrict__ f,
    float* __restrict__ kv) {
  int b = blockIdx.x >> 2, ks = blockIdx.x & 3;
  int wv = threadIdx.x >> 6, lane = threadIdx.x & 63;
  const float* u2 = uraw + ((size_t)NB + b) * ((size_t)NT * NC);
  const float* u3 = uraw + (2ull * NB + b) * ((size_t)NT * NC);
  const float* f2 = f + ((size_t)NB + b) * NC;
  const float* f3 = f + (2ull * NB + b) * NC;

  __shared__ float ldsF[16384];   // 64KB: per-wave [2][64][32]; reused for dump
  float* L2 = ldsF + wv * 4096;
  float* L3 = L2 + 2048;

  int tm = lane >> 3, tn = lane & 7;   // 8x8 lane grid over 64x64 tile
  int sr = lane >> 3, c4 = lane & 7;   // staging: 8 rows x 8 ch-quads

  float acc[8][8];
#pragma unroll
  for (int i = 0; i < 8; ++i)
#pragma unroll
    for (int j = 0; j < 8; ++j) acc[i][j] = 0.f;

  for (int chunk = 0; chunk < 4; ++chunk) {
    int ch0 = ks * 512 + wv * 128 + chunk * 32;
    float4 f2q = *reinterpret_cast<const float4*>(f2 + ch0 + c4 * 4);
    float4 f3q = *reinterpret_cast<const float4*>(f3 + ch0 + c4 * 4);
#pragma unroll
    for (int it = 0; it < 8; ++it) {
      int t = it * 8 + sr;
      int q4s = c4 ^ sr ^ it;          // = c4 ^ (t&7) ^ (t>>3)
      float4 v2 = *reinterpret_cast<const float4*>(u2 + (size_t)t * NC + ch0 + c4 * 4);
      float4 v3 = *reinterpret_cast<const float4*>(u3 + (size_t)t * NC + ch0 + c4 * 4);
      float4 w2 = {foc(v2.x, f2q.x), foc(v2.y, f2q.y), foc(v2.z, f2q.z), foc(v2.w, f2q.w)};
      float4 w3 = {foc(v3.x, f3q.x), foc(v3.y, f3q.y), foc(v3.z, f3q.z), foc(v3.w, f3q.w)};
      *reinterpret_cast<float4*>(L2 + t * 32 + q4s * 4) = w2;
      *reinterpret_cast<float4*>(L3 + t * 32 + q4s * 4) = w3;
    }

#pragma unroll
    for (int kp = 0; kp < 16; ++kp) {  // 16 ch-pairs of the 32-ch chunk
      int q4 = kp >> 1, h = (kp & 1) * 2;
      float2 af[8], bf[8];
#pragma unroll
      for (int i = 0; i < 8; ++i)
        af[i] = *reinterpret_cast<const float2*>(
            L2 + (tm * 8 + i) * 32 + ((q4 ^ i ^ tm) * 4 + h));
#pragma unroll
      for (int j = 0; j < 8; ++j)
        bf[j] = *reinterpret_cast<const float2*>(
            L3 + (tn * 8 + j) * 32 + ((q4 ^ j ^ tn) * 4 + h));
#pragma unroll
      for (int i = 0; i < 8; ++i)
#pragma unroll
        for (int j = 0; j < 8; ++j)
          acc[i][j] = fmaf(af[i].y, bf[j].y, fmaf(af[i].x, bf[j].x, acc[i][j]));
    }
  }

  // cross-wave reduce: waves 1..3 dump per-lane-contiguous (pad 66), wave 0 sums
  __syncthreads();
  if (wv > 0) {
    float* dp = ldsF + (wv - 1) * 4224 + lane * 66;
#pragma unroll
    for (int i = 0; i < 8; ++i)
#pragma unroll
      for (int j = 0; j < 8; ++j) dp[i * 8 + j] = acc[i][j];
  }
  __syncthreads();
  if (wv == 0) {
    float* kvp = kv + (size_t)b * (NT * NT);
    const float* d0 = ldsF + lane * 66;
    const float* d1 = ldsF + 4224 + lane * 66;
    const float* d2 = ldsF + 8448 + lane * 66;
#pragma unroll
    for (int i = 0; i < 8; ++i)
#pragma unroll
      for (int j = 0; j < 8; ++j) {
        int c = i * 8 + j;
        atomicAdd(&kvp[(tm * 8 + i) * 64 + tn * 8 + j],
                  acc[i][j] + d0[c] + d1[c] + d2[c]);
      }
  }
}

// ---------------------------------------------------------------------------
// K5: conv-weight transform (prefix-sum domain).
// ---------------------------------------------------------------------------
__global__ __launch_bounds__(64) void k_cwt(
    const float* __restrict__ cw, float* __restrict__ cwt) {
  int o = blockIdx.x;
  int tid = threadIdx.x;
  __shared__ float row[32 * KW];
  for (int i = tid; i < 32 * KW; i += 64) row[i] = cw[(size_t)o * (32 * KW) + i];
  __syncthreads();
  int jj = tid, j = jj + 1;
  for (int ci = 0; ci < 32; ++ci) {
    float v = 0.f;
    if (j <= 32) v -= row[ci * KW + j + 32];
    if (j >= 32 && j <= 63) v += row[ci * KW + j - 32];
    if (j == 64) {
      float s = 0.f;
      for (int k = 32; k <= 64; ++k) s += row[ci * KW + k];
      v += s;
    }
    cwt[(size_t)o * 2048 + ci * 64 + jj] = v;
  }
}

// ---------------------------------------------------------------------------
// K6: pre[b][ch][jj] = z[b,ch] * sum_t1 ut[t1,ch] * kvpre[t1][jj]
// grid: b(128) x ch8(8) = 1024 blocks (256 ch each), 256 threads
// ---------------------------------------------------------------------------
__global__ __launch_bounds__(256) void k_pre(
    const float* __restrict__ uraw, const float* __restrict__ f,
    const float* __restrict__ kvg, const float* __restrict__ s1g,
    float* __restrict__ pre) {
  int b = blockIdx.x >> 3, q = blockIdx.x & 7;
  int chbase = q * 256;
  const float* u1 = uraw + (size_t)b * ((size_t)NT * NC);
  const float* f1 = f + (size_t)b * NC;
  int tid = threadIdx.x;

  __shared__ float kvpreL[64][68];
  __shared__ float s1L[64];
  __shared__ float utL[64][132];   // [t][c4-skewed ch_local], skew c4*33

#pragma unroll
  for (int qq = 0; qq < 16; ++qq) {
    int i = tid + qq * 256;
    kvpreL[i >> 6][i & 63] = kvg[(size_t)b * (NT * NT) + i];
  }
  if (tid < 64) s1L[tid] = s1g[b * NT + tid];
  __syncthreads();
  if (tid < 64) {
    float run = 0.f;
    for (int t2 = 0; t2 < 64; ++t2) {
      run += kvpreL[tid][t2];
      kvpreL[tid][t2] = run;
    }
  }

  int cg = tid >> 3, tg = tid & 7;   // cg: 4-ch group, tg: 8-j group
  for (int tile = 0; tile < 2; ++tile) {
    int ch0 = chbase + tile * 128;
    __syncthreads();
    { // stage focused u1: utL[t][c4*33 + w] = u1'[b][ch0 + c4*32 + w][t]
      int t = tid >> 2, c4 = tid & 3;
      const float* up = u1 + (size_t)t * NC + ch0 + c4 * 32;
      const float* fp = f1 + ch0 + c4 * 32;
#pragma unroll
      for (int qq = 0; qq < 8; ++qq) {
        float4 v  = *reinterpret_cast<const float4*>(up + qq * 4);
        float4 fv = *reinterpret_cast<const float4*>(fp + qq * 4);
        float vv[4] = {v.x, v.y, v.z, v.w};
        float ff[4] = {fv.x, fv.y, fv.z, fv.w};
#pragma unroll
        for (int r = 0; r < 4; ++r) {
          float uu = (fmaxf(vv[r], 0.f) + 1e-6f) * 0.2f;
          utL[t][c4 * 33 + qq * 4 + r] = uu * uu * uu * ff[r];
        }
      }
    }
    __syncthreads();

    int cl = cg * 4;
    int sk = (cl >> 5) * 33 + (cl & 31);
    float acc[4][8];
#pragma unroll
    for (int r = 0; r < 4; ++r)
#pragma unroll
      for (int c = 0; c < 8; ++c) acc[r][c] = 0.f;
    float accz[4] = {0.f, 0.f, 0.f, 0.f};

#pragma unroll 4
    for (int t1 = 0; t1 < 64; ++t1) {
      float4 a = *reinterpret_cast<const float4*>(&utL[t1][sk]);
      float s = s1L[t1];
      float4 k0 = *reinterpret_cast<const float4*>(&kvpreL[t1][tg * 8]);
      float4 k1 = *reinterpret_cast<const float4*>(&kvpreL[t1][tg * 8 + 4]);
      float aa[4] = {a.x, a.y, a.z, a.w};
      float kk[8] = {k0.x, k0.y, k0.z, k0.w, k1.x, k1.y, k1.z, k1.w};
#pragma unroll
      for (int r = 0; r < 4; ++r) {
        accz[r] = fmaf(aa[r], s, accz[r]);
#pragma unroll
        for (int c = 0; c < 8; ++c)
          acc[r][c] = fmaf(aa[r], kk[c], acc[r][c]);
      }
    }
#pragma unroll
    for (int r = 0; r < 4; ++r) {
      float z = 1.f / (accz[r] + EPSZ);
      float* pp = pre + ((size_t)b * NC + ch0 + cl + r) * 64 + tg * 8;
      float4 o0 = {acc[r][0] * z, acc[r][1] * z, acc[r][2] * z, acc[r][3] * z};
      float4 o1 = {acc[r][4] * z, acc[r][5] * z, acc[r][6] * z, acc[r][7] * z};
      *reinterpret_cast<float4*>(pp)     = o0;
      *reinterpret_cast<float4*>(pp + 4) = o1;
    }
  }
}

// ---------------------------------------------------------------------------
// K7: per-g GEMM  ysum[b][o] = sum_{K=2048} cwt[g*32+o][K] * pre[b][g*32..][K]
// + xsum (= pre at jj=63 of channel o) + bias, then squash over o, store.
// grid: g(64) x bq(4) = 256 blocks (g-major for cwt L2 reuse), 256 threads,
// 2b x 2o register tile.  (R4-proven fused-epilogue version.)
// ---------------------------------------------------------------------------
__global__ __launch_bounds__(256) void k_gemm(
    const float* __restrict__ pre, const float* __restrict__ cwt,
    const float* __restrict__ cb, float* __restrict__ out) {
  int g = blockIdx.x >> 2, bq = blockIdx.x & 3;
  int b0 = bq * 32;
  int tid = threadIdx.x;
  int oh = tid & 15, bh = tid >> 4;   // o in {oh, oh+16}, b_local in {bh, bh+16}

  __shared__ float preL[32][68];
  __shared__ float cwtL[32][68];

  float a00 = 0.f, a01 = 0.f, a10 = 0.f, a11 = 0.f;
  float xs00 = 0.f, xs01 = 0.f, xs10 = 0.f, xs11 = 0.f;

  for (int kc = 0; kc < 32; ++kc) {
    __syncthreads();
    { // stage: 8 floats per thread each
      int r8 = tid >> 3, s8 = tid & 7;
      const float* ps = pre + ((size_t)(b0 + r8) * NC + g * 32) * 64 + kc * 64 + s8 * 8;
      float4 p0 = *reinterpret_cast<const float4*>(ps);
      float4 p1 = *reinterpret_cast<const float4*>(ps + 4);
      *reinterpret_cast<float4*>(&preL[r8][s8 * 8])     = p0;
      *reinterpret_cast<float4*>(&preL[r8][s8 * 8 + 4]) = p1;
      const float* cs = cwt + (size_t)(g * 32 + r8) * 2048 + kc * 64 + s8 * 8;
      float4 c0 = *reinterpret_cast<const float4*>(cs);
      float4 c1 = *reinterpret_cast<const float4*>(cs + 4);
      *reinterpret_cast<float4*>(&cwtL[r8][s8 * 8])     = c0;
      *reinterpret_cast<float4*>(&cwtL[r8][s8 * 8 + 4]) = c1;
    }
    __syncthreads();

    if (kc == oh)      { xs00 = preL[bh][63]; xs10 = preL[bh + 16][63]; }
    if (kc == oh + 16) { xs01 = preL[bh][63]; xs11 = preL[bh + 16][63]; }

#pragma unroll
    for (int kk = 0; kk < 64; kk += 4) {
      float4 p0 = *reinterpret_cast<const float4*>(&preL[bh][kk]);
      float4 p1 = *reinterpret_cast<const float4*>(&preL[bh + 16][kk]);
      float4 c0 = *reinterpret_cast<const float4*>(&cwtL[oh][kk]);
      float4 c1 = *reinterpret_cast<const float4*>(&cwtL[oh + 16][kk]);
      a00 = fmaf(p0.x, c0.x, a00); a00 = fmaf(p0.y, c0.y, a00);
      a00 = fmaf(p0.z, c0.z, a00); a00 = fmaf(p0.w, c0.w, a00);
      a01 = fmaf(p0.x, c1.x, a01); a01 = fmaf(p0.y, c1.y, a01);
      a01 = fmaf(p0.z, c1.z, a01); a01 = fmaf(p0.w, c1.w, a01);
      a10 = fmaf(p1.x, c0.x, a10); a10 = fmaf(p1.y, c0.y, a10);
      a10 = fmaf(p1.z, c0.z, a10); a10 = fmaf(p1.w, c0.w, a10);
      a11 = fmaf(p1.x, c1.x, a11); a11 = fmaf(p1.y, c1.y, a11);
      a11 = fmaf(p1.z, c1.z, a11); a11 = fmaf(p1.w, c1.w, a11);
    }
  }

  float cb0 = cb[g * 32 + oh], cb1 = cb[g * 32 + oh + 16];
  float v00 = a00 + xs00 + 64.f * cb0;   // (b=bh,    o=oh)
  float v01 = a01 + xs01 + 64.f * cb1;   // (b=bh,    o=oh+16)
  float v10 = a10 + xs10 + 64.f * cb0;   // (b=bh+16, o=oh)
  float v11 = a11 + xs11 + 64.f * cb1;   // (b=bh+16, o=oh+16)

  float sqA = v00 * v00 + v01 * v01;
  float sqB = v10 * v10 + v11 * v11;
#pragma unroll
  for (int m = 8; m >= 1; m >>= 1) {
    sqA += __shfl_xor(sqA, m, 16);
    sqB += __shfl_xor(sqB, m, 16);
  }
  float nA = sqrtf(sqA), nB = sqrtf(sqB);
  float cA = 1.f - 1.f / (expf(nA) + 1e-20f);
  float cB = 1.f - 1.f / (expf(nB) + 1e-20f);
  float iA = cA / (nA + 1e-20f), iB = cB / (nB + 1e-20f);

  size_t baseA = ((size_t)(b0 + bh) * NG + g) * ND;
  size_t baseB = ((size_t)(b0 + bh + 16) * NG + g) * ND;
  out[baseA + oh]      = v00 * iA;
  out[baseA + oh + 16] = v01 * iA;
  out[baseB + oh]      = v10 * iB;
  out[baseB + oh + 16] = v11 * iB;
}

// ---------------------------------------------------------------------------
extern "C" void kernel_launch(void* const* d_in, const int* in_sizes, int n_in,
                              void* d_out, int out_size, void* d_ws, size_t ws_size,
                              hipStream_t stream) {
  const float* x1 = (const float*)d_in[0];
  const float* x2 = (const float*)d_in[1];
  const float* x3 = (const float*)d_in[2];
  const float* W  = (const float*)d_in[3];
  const float* cw = (const float*)d_in[4];
  const float* cb = (const float*)d_in[5];
  float* out = (float*)d_out;

  float* ws   = (float*)d_ws;
  float* uraw = ws + OFF_URAW;
  float* f    = ws + OFF_F;
  float* s1   = ws + OFF_S1;
  float* kv   = ws + OFF_KV;
  // overlays (dead after k_kv):
  float* pre  = uraw + (size_t)NB * NT * NC;        // u2 region
  float* cwt  = uraw + 2ull * NB * NT * NC;         // u3 region

  k_transform<<<3072, 256, 0, stream>>>(x1, x2, x3, W, uraw);
  k_zero<<<256, 256, 0, stream>>>(s1, (int)(SZ_S1 + SZ_KV));
  k_factors<<<1536, 256, 0, stream>>>(uraw, f, s1);
  k_kv<<<512, 256, 0, stream>>>(uraw, f, kv);
  k_cwt<<<2048, 64, 0, stream>>>(cw, cwt);
  k_pre<<<1024, 256, 0, stream>>>(uraw, f, kv, s1, pre);
  k_gemm<<<256, 256, 0, stream>>>(pre, cwt, cb, out);
}

// Round 8
// 411.993 us; speedup vs baseline: 1.4483x; 1.0265x over previous
//
#include <hip/hip_runtime.h>
#include <cstddef>

// Problem constants
#define NB 128    // B
#define NT 64     // N0 (time/positions)
#define ND 32     // D0 == D1
#define NG 64     // N1 (groups/capsules)
#define NC 2048   // N1*D1 channels
#define KW 65     // conv kernel size
#define EPSZ 1.1920928955078125e-07f

// ws layout (floats)
#define OFF_URAW 0ull
#define SZ_URAW  (3ull * NB * NT * NC)
#define OFF_F    (OFF_URAW + SZ_URAW)
#define SZ_F     (3ull * NB * NC)
#define OFF_S1   (OFF_F + SZ_F)
#define SZ_S1    ((unsigned long long)NB * NT)
#define OFF_KV   (OFF_S1 + SZ_S1)
#define SZ_KV    ((unsigned long long)NB * NT * NT)
// overlays:
//   pre[b][ch][jj]  -> u2 region (dead after k_kv)
//   cwt[o][ci*64+jj]-> u3 region (dead after k_kv)

__device__ __forceinline__ float foc(float v, float fv) {
  float u = (fmaxf(v, 0.f) + 1e-6f) * 0.2f;
  return u * u * u * fv;
}

// ---------------------------------------------------------------------------
// K1: transform. For each j (0..63) a GEMM  [384 rows=(inp,b)] x [32 i] x [2048 c]
// writes u_raw[inp][b][t=j][ch=c]
// ---------------------------------------------------------------------------
__global__ __launch_bounds__(256) void k_transform(
    const float* __restrict__ x1, const float* __restrict__ x2,
    const float* __restrict__ x3, const float* __restrict__ W,
    float* __restrict__ uraw) {
  int bid = blockIdx.x;
  int j   = bid & 63;
  int nt  = (bid >> 6) & 15;
  int inp = bid >> 10;
  const float* x = (inp == 0) ? x1 : ((inp == 1) ? x2 : x3);
  float* uout = uraw + (size_t)inp * ((size_t)NB * NT * NC);

  __shared__ float as[32][132];  // [i][b]
  __shared__ float bs[32][132];  // [i][c_local]
  int tid = threadIdx.x;

  { // A tile: x[b][j][i]  -> as[i][b]
    int b = tid >> 1, h = tid & 1;
    const float* xp = x + ((size_t)b * NT + j) * ND + h * 16;
#pragma unroll
    for (int q = 0; q < 4; ++q) {
      float4 v = *reinterpret_cast<const float4*>(xp + q * 4);
      int i0 = h * 16 + q * 4;
      as[i0 + 0][b] = v.x; as[i0 + 1][b] = v.y;
      as[i0 + 2][b] = v.z; as[i0 + 3][b] = v.w;
    }
  }
  { // B tile: W[k0+kk][j][i][z] -> bs[i][kk*32+z]
    int kk = tid >> 6, u = tid & 63;
    int i = u >> 1, h = u & 1;
    const float* wp = W + (((size_t)(nt * 4 + kk) * NT + j) * ND + i) * ND + h * 16;
#pragma unroll
    for (int q = 0; q < 4; ++q) {
      float4 v = *reinterpret_cast<const float4*>(wp + q * 4);
      int c0 = kk * 32 + h * 16 + q * 4;
      bs[i][c0 + 0] = v.x; bs[i][c0 + 1] = v.y;
      bs[i][c0 + 2] = v.z; bs[i][c0 + 3] = v.w;
    }
  }
  __syncthreads();

  int tm = tid & 15, tn = tid >> 4;
  int m0 = tm * 8, n0 = tn * 8;
  float acc[8][8];
#pragma unroll
  for (int a = 0; a < 8; ++a)
#pragma unroll
    for (int c = 0; c < 8; ++c) acc[a][c] = 0.f;

#pragma unroll 4
  for (int kk = 0; kk < 32; ++kk) {
    float4 a0 = *reinterpret_cast<const float4*>(&as[kk][m0]);
    float4 a1 = *reinterpret_cast<const float4*>(&as[kk][m0 + 4]);
    float4 b0 = *reinterpret_cast<const float4*>(&bs[kk][n0]);
    float4 b1 = *reinterpret_cast<const float4*>(&bs[kk][n0 + 4]);
    float av[8] = {a0.x, a0.y, a0.z, a0.w, a1.x, a1.y, a1.z, a1.w};
    float bv[8] = {b0.x, b0.y, b0.z, b0.w, b1.x, b1.y, b1.z, b1.w};
#pragma unroll
    for (int mi = 0; mi < 8; ++mi)
#pragma unroll
      for (int ni = 0; ni < 8; ++ni)
        acc[mi][ni] = fmaf(av[mi], bv[ni], acc[mi][ni]);
  }

#pragma unroll
  for (int mi = 0; mi < 8; ++mi) {
    float* cp = uout + ((size_t)(m0 + mi) * NT + j) * NC + nt * 128 + n0;
    float4 v0 = {acc[mi][0], acc[mi][1], acc[mi][2], acc[mi][3]};
    float4 v1 = {acc[mi][4], acc[mi][5], acc[mi][6], acc[mi][7]};
    *reinterpret_cast<float4*>(cp)     = v0;
    *reinterpret_cast<float4*>(cp + 4) = v1;
  }
}

// ---------------------------------------------------------------------------
// K2: focus factors for INPUT 0 ONLY (f2/f3 are fused into k_kv now):
// f1 = sqrt(sum u'^2)/sqrt(sum u'^6), plus s1[b][t] = sum_ch u1'^3 * f1.
// grid: b(128) x quarter(4) = 512 blocks, 256 threads
// ---------------------------------------------------------------------------
__global__ __launch_bounds__(256) void k_factors(
    const float* __restrict__ uraw, float* __restrict__ f,
    float* __restrict__ s1) {
  int bid = blockIdx.x;
  int q = bid & 3, b = bid >> 2;
  const float* u = uraw + (size_t)b * ((size_t)NT * NC);
  int tid = threadIdx.x;
  int ch = q * 512 + tid * 2;

  float s2a = 0.f, s6a = 0.f, s2b = 0.f, s6b = 0.f;
  for (int t = 0; t < NT; ++t) {
    float2 v = *reinterpret_cast<const float2*>(u + (size_t)t * NC + ch);
    float ua = (fmaxf(v.x, 0.f) + 1e-6f) * 0.2f;
    float p2a = ua * ua, p3a = p2a * ua;
    s2a += p2a; s6a += p3a * p3a;
    float ub = (fmaxf(v.y, 0.f) + 1e-6f) * 0.2f;
    float p2b = ub * ub, p3b = p2b * ub;
    s2b += p2b; s6b += p3b * p3b;
  }
  float fa = sqrtf(s2a) / sqrtf(s6a);
  float fb = sqrtf(s2b) / sqrtf(s6b);
  float2 fv = {fa, fb};
  *reinterpret_cast<float2*>(f + (size_t)b * NC + ch) = fv;

  __shared__ float part[NT][4];
  int wid = tid >> 6, lane = tid & 63;
  for (int t = 0; t < NT; ++t) {
    float2 v = *reinterpret_cast<const float2*>(u + (size_t)t * NC + ch);
    float ua = (fmaxf(v.x, 0.f) + 1e-6f) * 0.2f;
    float ub = (fmaxf(v.y, 0.f) + 1e-6f) * 0.2f;
    float val = ua * ua * ua * fa + ub * ub * ub * fb;
#pragma unroll
    for (int m = 32; m >= 1; m >>= 1) val += __shfl_xor(val, m, 64);
    if (lane == 0) part[t][wid] = val;
  }
  __syncthreads();
  if (tid < NT)
    atomicAdd(&s1[b * NT + tid],
              part[tid][0] + part[tid][1] + part[tid][2] + part[tid][3]);
}

// ---------------------------------------------------------------------------
// K3: zero accumulators
// ---------------------------------------------------------------------------
__global__ void k_zero(float* __restrict__ p, int n) {
  int i = blockIdx.x * blockDim.x + threadIdx.x;
  int stride = gridDim.x * blockDim.x;
  for (; i < n; i += stride) p[i] = 0.f;
}

// ---------------------------------------------------------------------------
// K4 v4: kv[b][t1][t2] = sum_ch u2'[ch][t1]*u3'[ch][t2] with f2/f3 computed
// IN-KERNEL (fused).  Block = 4 waves sharing one 16KB swizzled staging
// buffer [2][64][32] per 32-ch chunk; each wave owns a 32x32 output quadrant
// (4x4 acc/lane -> ~64 VGPR).  Per chunk: stage raw (coalesced 128B rows) ->
// column s2/s6 sums (2 thr/col + shfl) -> foc in place -> Gram pass
// (XOR-swizzled conflict-free b64 reads, R7-verified).  Atomic epilogue.
// grid: b(128) x ks(8) = 1024 blocks, 256 threads -> 16 waves/CU.
// ---------------------------------------------------------------------------
__global__ __launch_bounds__(256) void k_kv(
    const float* __restrict__ uraw, float* __restrict__ kv) {
  int b = blockIdx.x >> 3, ks = blockIdx.x & 7;
  int tid = threadIdx.x;
  int wv = tid >> 6, lane = tid & 63;
  const float* u2 = uraw + ((size_t)NB + b) * ((size_t)NT * NC);
  const float* u3 = uraw + (2ull * NB + b) * ((size_t)NT * NC);

  __shared__ float L[2][64][32];   // swizzled: col quad q4s = q4 ^ (t&7) ^ (t>>3)
  __shared__ float fL[2][32];

  int q4 = tid & 7, tr = tid >> 3;             // staging map (tr 0..31)
  int colf = tid >> 1, hf = tid & 1;           // factor map: 2 threads/col
  int opf = colf >> 5, chf = colf & 31, c4f = chf >> 2, clf = chf & 3;
  int qr = wv >> 1, qc = wv & 1;               // wave quadrant
  int tm = lane >> 3, tn = lane & 7;

  float acc[4][4];
#pragma unroll
  for (int i = 0; i < 4; ++i)
#pragma unroll
    for (int j = 0; j < 4; ++j) acc[i][j] = 0.f;

  for (int chunk = 0; chunk < 8; ++chunk) {
    int ch0 = ks * 256 + chunk * 32;
    __syncthreads();   // previous gram reads done before restaging
    // ---- stage raw ----
#pragma unroll
    for (int it = 0; it < 2; ++it) {
      int t = it * 32 + tr;
      int q4s = q4 ^ (t & 7) ^ (t >> 3);
      float4 v2 = *reinterpret_cast<const float4*>(u2 + (size_t)t * NC + ch0 + q4 * 4);
      float4 v3 = *reinterpret_cast<const float4*>(u3 + (size_t)t * NC + ch0 + q4 * 4);
      *reinterpret_cast<float4*>(&L[0][t][q4s * 4]) = v2;
      *reinterpret_cast<float4*>(&L[1][t][q4s * 4]) = v3;
    }
    __syncthreads();
    // ---- factors: s2/s6 column sums ----
    {
      float s2 = 0.f, s6 = 0.f;
#pragma unroll
      for (int k = 0; k < 32; ++k) {
        int t = hf * 32 + k;
        float v = L[opf][t][((c4f ^ (t & 7) ^ (t >> 3)) << 2) + clf];
        float uu = (fmaxf(v, 0.f) + 1e-6f) * 0.2f;
        float p2 = uu * uu; s2 += p2;
        float p3 = p2 * uu; s6 += p3 * p3;
      }
      s2 += __shfl_xor(s2, 1, 64);
      s6 += __shfl_xor(s6, 1, 64);
      if (hf == 0) fL[opf][chf] = sqrtf(s2) / sqrtf(s6);
    }
    __syncthreads();
    // ---- foc in place ----
    {
      float4 f2q = *reinterpret_cast<const float4*>(&fL[0][q4 * 4]);
      float4 f3q = *reinterpret_cast<const float4*>(&fL[1][q4 * 4]);
#pragma unroll
      for (int it = 0; it < 2; ++it) {
        int t = it * 32 + tr;
        int q4s = q4 ^ (t & 7) ^ (t >> 3);
        float* p2p = &L[0][t][q4s * 4];
        float* p3p = &L[1][t][q4s * 4];
        float4 v2 = *reinterpret_cast<const float4*>(p2p);
        float4 v3 = *reinterpret_cast<const float4*>(p3p);
        float4 w2 = {foc(v2.x, f2q.x), foc(v2.y, f2q.y), foc(v2.z, f2q.z), foc(v2.w, f2q.w)};
        float4 w3 = {foc(v3.x, f3q.x), foc(v3.y, f3q.y), foc(v3.z, f3q.z), foc(v3.w, f3q.w)};
        *reinterpret_cast<float4*>(p2p) = w2;
        *reinterpret_cast<float4*>(p3p) = w3;
      }
    }
    __syncthreads();
    // ---- Gram pass over this chunk (quadrant per wave) ----
#pragma unroll
    for (int kp = 0; kp < 16; ++kp) {
      int qk = kp >> 1, h2 = (kp & 1) * 2;
      float2 af[4], bf[4];
#pragma unroll
      for (int i = 0; i < 4; ++i) {
        int t1 = qr * 32 + tm * 4 + i;
        af[i] = *reinterpret_cast<const float2*>(
            &L[0][t1][((qk ^ (t1 & 7) ^ (t1 >> 3)) << 2) + h2]);
      }
#pragma unroll
      for (int j = 0; j < 4; ++j) {
        int t2 = qc * 32 + tn * 4 + j;
        bf[j] = *reinterpret_cast<const float2*>(
            &L[1][t2][((qk ^ (t2 & 7) ^ (t2 >> 3)) << 2) + h2]);
      }
#pragma unroll
      for (int i = 0; i < 4; ++i)
#pragma unroll
        for (int j = 0; j < 4; ++j)
          acc[i][j] = fmaf(af[i].y, bf[j].y, fmaf(af[i].x, bf[j].x, acc[i][j]));
    }
  }

  float* kvp = kv + (size_t)b * (NT * NT);
#pragma unroll
  for (int i = 0; i < 4; ++i)
#pragma unroll
    for (int j = 0; j < 4; ++j)
      atomicAdd(&kvp[(qr * 32 + tm * 4 + i) * 64 + qc * 32 + tn * 4 + j],
                acc[i][j]);
}

// ---------------------------------------------------------------------------
// K5: conv-weight transform (prefix-sum domain).
// ---------------------------------------------------------------------------
__global__ __launch_bounds__(64) void k_cwt(
    const float* __restrict__ cw, float* __restrict__ cwt) {
  int o = blockIdx.x;
  int tid = threadIdx.x;
  __shared__ float row[32 * KW];
  for (int i = tid; i < 32 * KW; i += 64) row[i] = cw[(size_t)o * (32 * KW) + i];
  __syncthreads();
  int jj = tid, j = jj + 1;
  for (int ci = 0; ci < 32; ++ci) {
    float v = 0.f;
    if (j <= 32) v -= row[ci * KW + j + 32];
    if (j >= 32 && j <= 63) v += row[ci * KW + j - 32];
    if (j == 64) {
      float s = 0.f;
      for (int k = 32; k <= 64; ++k) s += row[ci * KW + k];
      v += s;
    }
    cwt[(size_t)o * 2048 + ci * 64 + jj] = v;
  }
}

// ---------------------------------------------------------------------------
// K6: pre[b][ch][jj] = z[b,ch] * sum_t1 ut[t1,ch] * kvpre[t1][jj]
// grid: b(128) x ch8(8) = 1024 blocks (256 ch each), 256 threads
// ---------------------------------------------------------------------------
__global__ __launch_bounds__(256) void k_pre(
    const float* __restrict__ uraw, const float* __restrict__ f,
    const float* __restrict__ kvg, const float* __restrict__ s1g,
    float* __restrict__ pre) {
  int b = blockIdx.x >> 3, q = blockIdx.x & 7;
  int chbase = q * 256;
  const float* u1 = uraw + (size_t)b * ((size_t)NT * NC);
  const float* f1 = f + (size_t)b * NC;
  int tid = threadIdx.x;

  __shared__ float kvpreL[64][68];
  __shared__ float s1L[64];
  __shared__ float utL[64][132];   // [t][c4-skewed ch_local], skew c4*33

#pragma unroll
  for (int qq = 0; qq < 16; ++qq) {
    int i = tid + qq * 256;
    kvpreL[i >> 6][i & 63] = kvg[(size_t)b * (NT * NT) + i];
  }
  if (tid < 64) s1L[tid] = s1g[b * NT + tid];
  __syncthreads();
  if (tid < 64) {
    float run = 0.f;
    for (int t2 = 0; t2 < 64; ++t2) {
      run += kvpreL[tid][t2];
      kvpreL[tid][t2] = run;
    }
  }

  int cg = tid >> 3, tg = tid & 7;   // cg: 4-ch group, tg: 8-j group
  for (int tile = 0; tile < 2; ++tile) {
    int ch0 = chbase + tile * 128;
    __syncthreads();
    { // stage focused u1: utL[t][c4*33 + w] = u1'[b][ch0 + c4*32 + w][t]
      int t = tid >> 2, c4 = tid & 3;
      const float* up = u1 + (size_t)t * NC + ch0 + c4 * 32;
      const float* fp = f1 + ch0 + c4 * 32;
#pragma unroll
      for (int qq = 0; qq < 8; ++qq) {
        float4 v  = *reinterpret_cast<const float4*>(up + qq * 4);
        float4 fv = *reinterpret_cast<const float4*>(fp + qq * 4);
        float vv[4] = {v.x, v.y, v.z, v.w};
        float ff[4] = {fv.x, fv.y, fv.z, fv.w};
#pragma unroll
        for (int r = 0; r < 4; ++r) {
          float uu = (fmaxf(vv[r], 0.f) + 1e-6f) * 0.2f;
          utL[t][c4 * 33 + qq * 4 + r] = uu * uu * uu * ff[r];
        }
      }
    }
    __syncthreads();

    int cl = cg * 4;
    int sk = (cl >> 5) * 33 + (cl & 31);
    float acc[4][8];
#pragma unroll
    for (int r = 0; r < 4; ++r)
#pragma unroll
      for (int c = 0; c < 8; ++c) acc[r][c] = 0.f;
    float accz[4] = {0.f, 0.f, 0.f, 0.f};

#pragma unroll 4
    for (int t1 = 0; t1 < 64; ++t1) {
      float4 a = *reinterpret_cast<const float4*>(&utL[t1][sk]);
      float s = s1L[t1];
      float4 k0 = *reinterpret_cast<const float4*>(&kvpreL[t1][tg * 8]);
      float4 k1 = *reinterpret_cast<const float4*>(&kvpreL[t1][tg * 8 + 4]);
      float aa[4] = {a.x, a.y, a.z, a.w};
      float kk[8] = {k0.x, k0.y, k0.z, k0.w, k1.x, k1.y, k1.z, k1.w};
#pragma unroll
      for (int r = 0; r < 4; ++r) {
        accz[r] = fmaf(aa[r], s, accz[r]);
#pragma unroll
        for (int c = 0; c < 8; ++c)
          acc[r][c] = fmaf(aa[r], kk[c], acc[r][c]);
      }
    }
#pragma unroll
    for (int r = 0; r < 4; ++r) {
      float z = 1.f / (accz[r] + EPSZ);
      float* pp = pre + ((size_t)b * NC + ch0 + cl + r) * 64 + tg * 8;
      float4 o0 = {acc[r][0] * z, acc[r][1] * z, acc[r][2] * z, acc[r][3] * z};
      float4 o1 = {acc[r][4] * z, acc[r][5] * z, acc[r][6] * z, acc[r][7] * z};
      *reinterpret_cast<float4*>(pp)     = o0;
      *reinterpret_cast<float4*>(pp + 4) = o1;
    }
  }
}

// ---------------------------------------------------------------------------
// K7: per-g GEMM  ysum[b][o] = sum_{K=2048} cwt[g*32+o][K] * pre[b][g*32..][K]
// + xsum (= pre at jj=63 of channel o) + bias, then squash over o, store.
// grid: g(64) x bq(4) = 256 blocks, 256 threads, 2b x 2o register tile.
// ---------------------------------------------------------------------------
__global__ __launch_bounds__(256) void k_gemm(
    const float* __restrict__ pre, const float* __restrict__ cwt,
    const float* __restrict__ cb, float* __restrict__ out) {
  int g = blockIdx.x >> 2, bq = blockIdx.x & 3;
  int b0 = bq * 32;
  int tid = threadIdx.x;
  int oh = tid & 15, bh = tid >> 4;   // o in {oh, oh+16}, b_local in {bh, bh+16}

  __shared__ float preL[32][68];
  __shared__ float cwtL[32][68];

  float a00 = 0.f, a01 = 0.f, a10 = 0.f, a11 = 0.f;
  float xs00 = 0.f, xs01 = 0.f, xs10 = 0.f, xs11 = 0.f;

  for (int kc = 0; kc < 32; ++kc) {
    __syncthreads();
    { // stage: 8 floats per thread each
      int r8 = tid >> 3, s8 = tid & 7;
      const float* ps = pre + ((size_t)(b0 + r8) * NC + g * 32) * 64 + kc * 64 + s8 * 8;
      float4 p0 = *reinterpret_cast<const float4*>(ps);
      float4 p1 = *reinterpret_cast<const float4*>(ps + 4);
      *reinterpret_cast<float4*>(&preL[r8][s8 * 8])     = p0;
      *reinterpret_cast<float4*>(&preL[r8][s8 * 8 + 4]) = p1;
      const float* cs = cwt + (size_t)(g * 32 + r8) * 2048 + kc * 64 + s8 * 8;
      float4 c0 = *reinterpret_cast<const float4*>(cs);
      float4 c1 = *reinterpret_cast<const float4*>(cs + 4);
      *reinterpret_cast<float4*>(&cwtL[r8][s8 * 8])     = c0;
      *reinterpret_cast<float4*>(&cwtL[r8][s8 * 8 + 4]) = c1;
    }
    __syncthreads();

    if (kc == oh)      { xs00 = preL[bh][63]; xs10 = preL[bh + 16][63]; }
    if (kc == oh + 16) { xs01 = preL[bh][63]; xs11 = preL[bh + 16][63]; }

#pragma unroll
    for (int kk = 0; kk < 64; kk += 4) {
      float4 p0 = *reinterpret_cast<const float4*>(&preL[bh][kk]);
      float4 p1 = *reinterpret_cast<const float4*>(&preL[bh + 16][kk]);
      float4 c0 = *reinterpret_cast<const float4*>(&cwtL[oh][kk]);
      float4 c1 = *reinterpret_cast<const float4*>(&cwtL[oh + 16][kk]);
      a00 = fmaf(p0.x, c0.x, a00); a00 = fmaf(p0.y, c0.y, a00);
      a00 = fmaf(p0.z, c0.z, a00); a00 = fmaf(p0.w, c0.w, a00);
      a01 = fmaf(p0.x, c1.x, a01); a01 = fmaf(p0.y, c1.y, a01);
      a01 = fmaf(p0.z, c1.z, a01); a01 = fmaf(p0.w, c1.w, a01);
      a10 = fmaf(p1.x, c0.x, a10); a10 = fmaf(p1.y, c0.y, a10);
      a10 = fmaf(p1.z, c0.z, a10); a10 = fmaf(p1.w, c0.w, a10);
      a11 = fmaf(p1.x, c1.x, a11); a11 = fmaf(p1.y, c1.y, a11);
      a11 = fmaf(p1.z, c1.z, a11); a11 = fmaf(p1.w, c1.w, a11);
    }
  }

  float cb0 = cb[g * 32 + oh], cb1 = cb[g * 32 + oh + 16];
  float v00 = a00 + xs00 + 64.f * cb0;   // (b=bh,    o=oh)
  float v01 = a01 + xs01 + 64.f * cb1;   // (b=bh,    o=oh+16)
  float v10 = a10 + xs10 + 64.f * cb0;   // (b=bh+16, o=oh)
  float v11 = a11 + xs11 + 64.f * cb1;   // (b=bh+16, o=oh+16)

  float sqA = v00 * v00 + v01 * v01;
  float sqB = v10 * v10 + v11 * v11;
#pragma unroll
  for (int m = 8; m >= 1; m >>= 1) {
    sqA += __shfl_xor(sqA, m, 16);
    sqB += __shfl_xor(sqB, m, 16);
  }
  float nA = sqrtf(sqA), nB = sqrtf(sqB);
  float cA = 1.f - 1.f / (expf(nA) + 1e-20f);
  float cB = 1.f - 1.f / (expf(nB) + 1e-20f);
  float iA = cA / (nA + 1e-20f), iB = cB / (nB + 1e-20f);

  size_t baseA = ((size_t)(b0 + bh) * NG + g) * ND;
  size_t baseB = ((size_t)(b0 + bh + 16) * NG + g) * ND;
  out[baseA + oh]      = v00 * iA;
  out[baseA + oh + 16] = v01 * iA;
  out[baseB + oh]      = v10 * iB;
  out[baseB + oh + 16] = v11 * iB;
}

// ---------------------------------------------------------------------------
extern "C" void kernel_launch(void* const* d_in, const int* in_sizes, int n_in,
                              void* d_out, int out_size, void* d_ws, size_t ws_size,
                              hipStream_t stream) {
  const float* x1 = (const float*)d_in[0];
  const float* x2 = (const float*)d_in[1];
  const float* x3 = (const float*)d_in[2];
  const float* W  = (const float*)d_in[3];
  const float* cw = (const float*)d_in[4];
  const float* cb = (const float*)d_in[5];
  float* out = (float*)d_out;

  float* ws   = (float*)d_ws;
  float* uraw = ws + OFF_URAW;
  float* f    = ws + OFF_F;
  float* s1   = ws + OFF_S1;
  float* kv   = ws + OFF_KV;
  // overlays (dead after k_kv):
  float* pre  = uraw + (size_t)NB * NT * NC;        // u2 region
  float* cwt  = uraw + 2ull * NB * NT * NC;         // u3 region

  k_transform<<<3072, 256, 0, stream>>>(x1, x2, x3, W, uraw);
  k_zero<<<256, 256, 0, stream>>>(s1, (int)(SZ_S1 + SZ_KV));
  k_factors<<<512, 256, 0, stream>>>(uraw, f, s1);
  k_kv<<<1024, 256, 0, stream>>>(uraw, kv);
  k_cwt<<<2048, 64, 0, stream>>>(cw, cwt);
  k_pre<<<1024, 256, 0, stream>>>(uraw, f, kv, s1, pre);
  k_gemm<<<256, 256, 0, stream>>>(pre, cwt, cb, out);
}

// Round 9
// 365.252 us; speedup vs baseline: 1.6337x; 1.1280x over previous
//
#include <hip/hip_runtime.h>
#include <hip/hip_fp16.h>
#include <cstddef>

// Problem constants
#define NB 128    // B
#define NT 64     // N0 (time/positions)
#define ND 32     // D0 == D1
#define NG 64     // N1 (groups/capsules)
#define NC 2048   // N1*D1 channels
#define KW 65     // conv kernel size
#define EPSZ 1.1920928955078125e-07f

// ws layout (in float units). uraw is now __half (f16 intermediate).
//   uraw   : 3*NB*NT*NC halves  = 25.17M floats   [0 .. 25.17M)
//   pre    : overlays u2+u3 half region: float offset NB*NT*NC/2, 16.77M floats
//   f      : NB*NC floats (inp0 factors)
//   s1     : NB*NT
//   kv     : NB*NT*NT
//   cwt    : NC*2048 floats
#define URAW_HALVES   (3ull * NB * NT * NC)
#define URAW_FLOATS   (URAW_HALVES / 2)
#define PRE_OFF       ((size_t)NB * NT * NC / 2)

__device__ __forceinline__ float foc(float v, float fv) {
  float u = (fmaxf(v, 0.f) + 1e-6f) * 0.2f;
  return u * u * u * fv;
}

// ---------------------------------------------------------------------------
// K1: transform. For each j (0..63) a GEMM  [384 rows=(inp,b)] x [32 i] x [2048 c]
// writes u_raw[inp][b][t=j][ch=c] as f16 (halves HBM write traffic).
// ---------------------------------------------------------------------------
__global__ __launch_bounds__(256) void k_transform(
    const float* __restrict__ x1, const float* __restrict__ x2,
    const float* __restrict__ x3, const float* __restrict__ W,
    __half* __restrict__ uraw) {
  int bid = blockIdx.x;
  int j   = bid & 63;
  int nt  = (bid >> 6) & 15;
  int inp = bid >> 10;
  const float* x = (inp == 0) ? x1 : ((inp == 1) ? x2 : x3);
  __half* uout = uraw + (size_t)inp * ((size_t)NB * NT * NC);

  __shared__ float as[32][132];  // [i][b]
  __shared__ float bs[32][132];  // [i][c_local]
  int tid = threadIdx.x;

  { // A tile: x[b][j][i]  -> as[i][b]
    int b = tid >> 1, h = tid & 1;
    const float* xp = x + ((size_t)b * NT + j) * ND + h * 16;
#pragma unroll
    for (int q = 0; q < 4; ++q) {
      float4 v = *reinterpret_cast<const float4*>(xp + q * 4);
      int i0 = h * 16 + q * 4;
      as[i0 + 0][b] = v.x; as[i0 + 1][b] = v.y;
      as[i0 + 2][b] = v.z; as[i0 + 3][b] = v.w;
    }
  }
  { // B tile: W[k0+kk][j][i][z] -> bs[i][kk*32+z]
    int kk = tid >> 6, u = tid & 63;
    int i = u >> 1, h = u & 1;
    const float* wp = W + (((size_t)(nt * 4 + kk) * NT + j) * ND + i) * ND + h * 16;
#pragma unroll
    for (int q = 0; q < 4; ++q) {
      float4 v = *reinterpret_cast<const float4*>(wp + q * 4);
      int c0 = kk * 32 + h * 16 + q * 4;
      bs[i][c0 + 0] = v.x; bs[i][c0 + 1] = v.y;
      bs[i][c0 + 2] = v.z; bs[i][c0 + 3] = v.w;
    }
  }
  __syncthreads();

  int tm = tid & 15, tn = tid >> 4;
  int m0 = tm * 8, n0 = tn * 8;
  float acc[8][8];
#pragma unroll
  for (int a = 0; a < 8; ++a)
#pragma unroll
    for (int c = 0; c < 8; ++c) acc[a][c] = 0.f;

#pragma unroll 4
  for (int kk = 0; kk < 32; ++kk) {
    float4 a0 = *reinterpret_cast<const float4*>(&as[kk][m0]);
    float4 a1 = *reinterpret_cast<const float4*>(&as[kk][m0 + 4]);
    float4 b0 = *reinterpret_cast<const float4*>(&bs[kk][n0]);
    float4 b1 = *reinterpret_cast<const float4*>(&bs[kk][n0 + 4]);
    float av[8] = {a0.x, a0.y, a0.z, a0.w, a1.x, a1.y, a1.z, a1.w};
    float bv[8] = {b0.x, b0.y, b0.z, b0.w, b1.x, b1.y, b1.z, b1.w};
#pragma unroll
    for (int mi = 0; mi < 8; ++mi)
#pragma unroll
      for (int ni = 0; ni < 8; ++ni)
        acc[mi][ni] = fmaf(av[mi], bv[ni], acc[mi][ni]);
  }

#pragma unroll
  for (int mi = 0; mi < 8; ++mi) {
    __half* cp = uout + ((size_t)(m0 + mi) * NT + j) * NC + nt * 128 + n0;
    __half2 hh[4];
    hh[0] = __floats2half2_rn(acc[mi][0], acc[mi][1]);
    hh[1] = __floats2half2_rn(acc[mi][2], acc[mi][3]);
    hh[2] = __floats2half2_rn(acc[mi][4], acc[mi][5]);
    hh[3] = __floats2half2_rn(acc[mi][6], acc[mi][7]);
    *reinterpret_cast<float4*>(cp) = *reinterpret_cast<const float4*>(hh);
  }
}

// ---------------------------------------------------------------------------
// K2: focus factors for INPUT 0 ONLY: f1 + s1[b][t] = sum_ch u1'^3*f1.
// grid: b(128) x quarter(4) = 512 blocks, 256 threads, f16 loads
// ---------------------------------------------------------------------------
__global__ __launch_bounds__(256) void k_factors(
    const __half* __restrict__ uraw, float* __restrict__ f,
    float* __restrict__ s1) {
  int bid = blockIdx.x;
  int q = bid & 3, b = bid >> 2;
  const __half* u = uraw + (size_t)b * ((size_t)NT * NC);
  int tid = threadIdx.x;
  int ch = q * 512 + tid * 2;

  float s2a = 0.f, s6a = 0.f, s2b = 0.f, s6b = 0.f;
  for (int t = 0; t < NT; ++t) {
    float2 v = __half22float2(*reinterpret_cast<const __half2*>(u + (size_t)t * NC + ch));
    float ua = (fmaxf(v.x, 0.f) + 1e-6f) * 0.2f;
    float p2a = ua * ua, p3a = p2a * ua;
    s2a += p2a; s6a += p3a * p3a;
    float ub = (fmaxf(v.y, 0.f) + 1e-6f) * 0.2f;
    float p2b = ub * ub, p3b = p2b * ub;
    s2b += p2b; s6b += p3b * p3b;
  }
  float fa = sqrtf(s2a) / sqrtf(s6a);
  float fb = sqrtf(s2b) / sqrtf(s6b);
  float2 fv = {fa, fb};
  *reinterpret_cast<float2*>(f + (size_t)b * NC + ch) = fv;

  __shared__ float part[NT][4];
  int wid = tid >> 6, lane = tid & 63;
  for (int t = 0; t < NT; ++t) {
    float2 v = __half22float2(*reinterpret_cast<const __half2*>(u + (size_t)t * NC + ch));
    float ua = (fmaxf(v.x, 0.f) + 1e-6f) * 0.2f;
    float ub = (fmaxf(v.y, 0.f) + 1e-6f) * 0.2f;
    float val = ua * ua * ua * fa + ub * ub * ub * fb;
#pragma unroll
    for (int m = 32; m >= 1; m >>= 1) val += __shfl_xor(val, m, 64);
    if (lane == 0) part[t][wid] = val;
  }
  __syncthreads();
  if (tid < NT)
    atomicAdd(&s1[b * NT + tid],
              part[tid][0] + part[tid][1] + part[tid][2] + part[tid][3]);
}

// ---------------------------------------------------------------------------
// K3: zero accumulators
// ---------------------------------------------------------------------------
__global__ void k_zero(float* __restrict__ p, int n) {
  int i = blockIdx.x * blockDim.x + threadIdx.x;
  int stride = gridDim.x * blockDim.x;
  for (; i < n; i += stride) p[i] = 0.f;
}

// ---------------------------------------------------------------------------
// K4 v5: kv[b][t1][t2] = sum_ch u2'[ch][t1]*u3'[ch][t2] (focused), f16 input.
// Pad-stride-34 LDS rows (no XOR): Gram reads are base + kp*8B IMMEDIATE
// offsets (zero addr VALU in hot loop), 2-way banks (free).  Factor phase:
// 16-lane shuffle-reduce over conflict-free float2 column reads.  Quadrant
// split (4x4 acc/lane), 17.4KB LDS, grid b(128) x ks(8) = 1024 blocks.
// ---------------------------------------------------------------------------
__global__ __launch_bounds__(256) void k_kv(
    const __half* __restrict__ uraw, float* __restrict__ kv) {
  int b = blockIdx.x >> 3, ks = blockIdx.x & 7;
  int tid = threadIdx.x;
  int wv = tid >> 6, lane = tid & 63;
  const __half* u2 = uraw + ((size_t)NB + b) * ((size_t)NT * NC);
  const __half* u3 = uraw + (2ull * NB + b) * ((size_t)NT * NC);

  __shared__ float L[2][64][34];   // stride 34: 4-row spacing -> 2-way banks
  __shared__ float fL[2][32];

  int oc = tid & 3, ts = tid >> 2;            // staging: row ts, ch-oct oc
  int qcf = lane >> 4, tseg = lane & 15;      // factor: quad-col wv*4+qcf
  int qqf = wv * 4 + qcf;
  int opf = qqf >> 3, c4f = qqf & 7;
  int qr = wv >> 1, qcw = wv & 1;             // wave output quadrant
  int tm = lane >> 3, tn = lane & 7;

  float acc[4][4];
#pragma unroll
  for (int i = 0; i < 4; ++i)
#pragma unroll
    for (int j = 0; j < 4; ++j) acc[i][j] = 0.f;

  for (int chunk = 0; chunk < 8; ++chunk) {
    int ch0 = ks * 256 + chunk * 32;
    __syncthreads();
    { // ---- stage raw (f16 -> f32), coalesced 16B loads ----
      float4 r2 = *reinterpret_cast<const float4*>(u2 + (size_t)ts * NC + ch0 + oc * 8);
      float4 r3 = *reinterpret_cast<const float4*>(u3 + (size_t)ts * NC + ch0 + oc * 8);
      const __half2* h2p = reinterpret_cast<const __half2*>(&r2);
      const __half2* h3p = reinterpret_cast<const __half2*>(&r3);
      float* d2 = &L[0][ts][oc * 8];
      float* d3 = &L[1][ts][oc * 8];
#pragma unroll
      for (int k = 0; k < 4; ++k) {
        float2 a = __half22float2(h2p[k]);
        float2 c = __half22float2(h3p[k]);
        *reinterpret_cast<float2*>(d2 + 2 * k) = a;
        *reinterpret_cast<float2*>(d3 + 2 * k) = c;
      }
    }
    __syncthreads();
    { // ---- factors: per-channel s2/s6, 16-lane shuffle reduce ----
      float s2[4] = {0.f, 0.f, 0.f, 0.f}, s6[4] = {0.f, 0.f, 0.f, 0.f};
#pragma unroll
      for (int r = 0; r < 4; ++r) {
        int t = tseg + 16 * r;
        float2 p0 = *reinterpret_cast<const float2*>(&L[opf][t][c4f * 4]);
        float2 p1 = *reinterpret_cast<const float2*>(&L[opf][t][c4f * 4 + 2]);
        float vv[4] = {p0.x, p0.y, p1.x, p1.y};
#pragma unroll
        for (int c = 0; c < 4; ++c) {
          float uu = (fmaxf(vv[c], 0.f) + 1e-6f) * 0.2f;
          float p2 = uu * uu; s2[c] += p2;
          float p3 = p2 * uu; s6[c] += p3 * p3;
        }
      }
#pragma unroll
      for (int m = 8; m >= 1; m >>= 1)
#pragma unroll
        for (int c = 0; c < 4; ++c) {
          s2[c] += __shfl_xor(s2[c], m, 16);
          s6[c] += __shfl_xor(s6[c], m, 16);
        }
      if (tseg == 0)
#pragma unroll
        for (int c = 0; c < 4; ++c)
          fL[opf][c4f * 4 + c] = sqrtf(s2[c]) / sqrtf(s6[c]);
    }
    __syncthreads();
    { // ---- foc in place (each thread its staged row segment) ----
      float fa[8], fb[8];
#pragma unroll
      for (int k = 0; k < 8; ++k) { fa[k] = fL[0][oc * 8 + k]; fb[k] = fL[1][oc * 8 + k]; }
      float* d2 = &L[0][ts][oc * 8];
      float* d3 = &L[1][ts][oc * 8];
#pragma unroll
      for (int k = 0; k < 4; ++k) {
        float2 a = *reinterpret_cast<const float2*>(d2 + 2 * k);
        float2 c = *reinterpret_cast<const float2*>(d3 + 2 * k);
        a.x = foc(a.x, fa[2 * k]); a.y = foc(a.y, fa[2 * k + 1]);
        c.x = foc(c.x, fb[2 * k]); c.y = foc(c.y, fb[2 * k + 1]);
        *reinterpret_cast<float2*>(d2 + 2 * k) = a;
        *reinterpret_cast<float2*>(d3 + 2 * k) = c;
      }
    }
    __syncthreads();
    // ---- Gram pass: immediate-offset b64 reads, 32 FMA per kp ----
#pragma unroll
    for (int kp = 0; kp < 16; ++kp) {
      float2 af[4], bf[4];
#pragma unroll
      for (int i = 0; i < 4; ++i)
        af[i] = *reinterpret_cast<const float2*>(&L[0][qr * 32 + tm * 4 + i][kp * 2]);
#pragma unroll
      for (int j = 0; j < 4; ++j)
        bf[j] = *reinterpret_cast<const float2*>(&L[1][qcw * 32 + tn * 4 + j][kp * 2]);
#pragma unroll
      for (int i = 0; i < 4; ++i)
#pragma unroll
        for (int j = 0; j < 4; ++j)
          acc[i][j] = fmaf(af[i].y, bf[j].y, fmaf(af[i].x, bf[j].x, acc[i][j]));
    }
  }

  float* kvp = kv + (size_t)b * (NT * NT);
#pragma unroll
  for (int i = 0; i < 4; ++i)
#pragma unroll
    for (int j = 0; j < 4; ++j)
      atomicAdd(&kvp[(qr * 32 + tm * 4 + i) * 64 + qcw * 32 + tn * 4 + j],
                acc[i][j]);
}

// ---------------------------------------------------------------------------
// K5: conv-weight transform (prefix-sum domain).
// ---------------------------------------------------------------------------
__global__ __launch_bounds__(64) void k_cwt(
    const float* __restrict__ cw, float* __restrict__ cwt) {
  int o = blockIdx.x;
  int tid = threadIdx.x;
  __shared__ float row[32 * KW];
  for (int i = tid; i < 32 * KW; i += 64) row[i] = cw[(size_t)o * (32 * KW) + i];
  __syncthreads();
  int jj = tid, j = jj + 1;
  for (int ci = 0; ci < 32; ++ci) {
    float v = 0.f;
    if (j <= 32) v -= row[ci * KW + j + 32];
    if (j >= 32 && j <= 63) v += row[ci * KW + j - 32];
    if (j == 64) {
      float s = 0.f;
      for (int k = 32; k <= 64; ++k) s += row[ci * KW + k];
      v += s;
    }
    cwt[(size_t)o * 2048 + ci * 64 + jj] = v;
  }
}

// ---------------------------------------------------------------------------
// K6: pre[b][ch][jj] = z[b,ch] * sum_t1 ut[t1,ch] * kvpre[t1][jj]; f16 u1.
// grid: b(128) x ch8(8) = 1024 blocks (256 ch each), 256 threads
// ---------------------------------------------------------------------------
__global__ __launch_bounds__(256) void k_pre(
    const __half* __restrict__ uraw, const float* __restrict__ f,
    const float* __restrict__ kvg, const float* __restrict__ s1g,
    float* __restrict__ pre) {
  int b = blockIdx.x >> 3, q = blockIdx.x & 7;
  int chbase = q * 256;
  const __half* u1 = uraw + (size_t)b * ((size_t)NT * NC);
  const float* f1 = f + (size_t)b * NC;
  int tid = threadIdx.x;

  __shared__ float kvpreL[64][68];
  __shared__ float s1L[64];
  __shared__ float utL[64][132];   // [t][c4-skewed ch_local], skew c4*33

#pragma unroll
  for (int qq = 0; qq < 16; ++qq) {
    int i = tid + qq * 256;
    kvpreL[i >> 6][i & 63] = kvg[(size_t)b * (NT * NT) + i];
  }
  if (tid < 64) s1L[tid] = s1g[b * NT + tid];
  __syncthreads();
  if (tid < 64) {
    float run = 0.f;
    for (int t2 = 0; t2 < 64; ++t2) {
      run += kvpreL[tid][t2];
      kvpreL[tid][t2] = run;
    }
  }

  int cg = tid >> 3, tg = tid & 7;   // cg: 4-ch group, tg: 8-j group
  for (int tile = 0; tile < 2; ++tile) {
    int ch0 = chbase + tile * 128;
    __syncthreads();
    { // stage focused u1: utL[t][c4*33 + w] = u1'[b][ch0 + c4*32 + w][t]
      int t = tid >> 2, c4 = tid & 3;
      const __half* up = u1 + (size_t)t * NC + ch0 + c4 * 32;
      const float* fp = f1 + ch0 + c4 * 32;
#pragma unroll
      for (int qq = 0; qq < 4; ++qq) {
        float4 raw = *reinterpret_cast<const float4*>(up + qq * 8);
        const __half2* hp = reinterpret_cast<const __half2*>(&raw);
        float4 fv0 = *reinterpret_cast<const float4*>(fp + qq * 8);
        float4 fv1 = *reinterpret_cast<const float4*>(fp + qq * 8 + 4);
        float ff[8] = {fv0.x, fv0.y, fv0.z, fv0.w, fv1.x, fv1.y, fv1.z, fv1.w};
#pragma unroll
        for (int r = 0; r < 4; ++r) {
          float2 uv = __half22float2(hp[r]);
          float ua = (fmaxf(uv.x, 0.f) + 1e-6f) * 0.2f;
          float ub = (fmaxf(uv.y, 0.f) + 1e-6f) * 0.2f;
          utL[t][c4 * 33 + qq * 8 + r * 2]     = ua * ua * ua * ff[r * 2];
          utL[t][c4 * 33 + qq * 8 + r * 2 + 1] = ub * ub * ub * ff[r * 2 + 1];
        }
      }
    }
    __syncthreads();

    int cl = cg * 4;
    int sk = (cl >> 5) * 33 + (cl & 31);
    float acc[4][8];
#pragma unroll
    for (int r = 0; r < 4; ++r)
#pragma unroll
      for (int c = 0; c < 8; ++c) acc[r][c] = 0.f;
    float accz[4] = {0.f, 0.f, 0.f, 0.f};

#pragma unroll 4
    for (int t1 = 0; t1 < 64; ++t1) {
      float4 a = *reinterpret_cast<const float4*>(&utL[t1][sk]);
      float s = s1L[t1];
      float4 k0 = *reinterpret_cast<const float4*>(&kvpreL[t1][tg * 8]);
      float4 k1 = *reinterpret_cast<const float4*>(&kvpreL[t1][tg * 8 + 4]);
      float aa[4] = {a.x, a.y, a.z, a.w};
      float kk[8] = {k0.x, k0.y, k0.z, k0.w, k1.x, k1.y, k1.z, k1.w};
#pragma unroll
      for (int r = 0; r < 4; ++r) {
        accz[r] = fmaf(aa[r], s, accz[r]);
#pragma unroll
        for (int c = 0; c < 8; ++c)
          acc[r][c] = fmaf(aa[r], kk[c], acc[r][c]);
      }
    }
#pragma unroll
    for (int r = 0; r < 4; ++r) {
      float z = 1.f / (accz[r] + EPSZ);
      float* pp = pre + ((size_t)b * NC + ch0 + cl + r) * 64 + tg * 8;
      float4 o0 = {acc[r][0] * z, acc[r][1] * z, acc[r][2] * z, acc[r][3] * z};
      float4 o1 = {acc[r][4] * z, acc[r][5] * z, acc[r][6] * z, acc[r][7] * z};
      *reinterpret_cast<float4*>(pp)     = o0;
      *reinterpret_cast<float4*>(pp + 4) = o1;
    }
  }
}

// ---------------------------------------------------------------------------
// K7: per-g GEMM  ysum[b][o] = sum_{K=2048} cwt[g*32+o][K] * pre[b][g*32..][K]
// + xsum + bias, squash over o, store.
// grid: g(64) x bq(4) = 256 blocks, 256 threads, 2b x 2o register tile.
// ---------------------------------------------------------------------------
__global__ __launch_bounds__(256) void k_gemm(
    const float* __restrict__ pre, const float* __restrict__ cwt,
    const float* __restrict__ cb, float* __restrict__ out) {
  int g = blockIdx.x >> 2, bq = blockIdx.x & 3;
  int b0 = bq * 32;
  int tid = threadIdx.x;
  int oh = tid & 15, bh = tid >> 4;   // o in {oh, oh+16}, b_local in {bh, bh+16}

  __shared__ float preL[32][68];
  __shared__ float cwtL[32][68];

  float a00 = 0.f, a01 = 0.f, a10 = 0.f, a11 = 0.f;
  float xs00 = 0.f, xs01 = 0.f, xs10 = 0.f, xs11 = 0.f;

  for (int kc = 0; kc < 32; ++kc) {
    __syncthreads();
    { // stage: 8 floats per thread each
      int r8 = tid >> 3, s8 = tid & 7;
      const float* ps = pre + ((size_t)(b0 + r8) * NC + g * 32) * 64 + kc * 64 + s8 * 8;
      float4 p0 = *reinterpret_cast<const float4*>(ps);
      float4 p1 = *reinterpret_cast<const float4*>(ps + 4);
      *reinterpret_cast<float4*>(&preL[r8][s8 * 8])     = p0;
      *reinterpret_cast<float4*>(&preL[r8][s8 * 8 + 4]) = p1;
      const float* cs = cwt + (size_t)(g * 32 + r8) * 2048 + kc * 64 + s8 * 8;
      float4 c0 = *reinterpret_cast<const float4*>(cs);
      float4 c1 = *reinterpret_cast<const float4*>(cs + 4);
      *reinterpret_cast<float4*>(&cwtL[r8][s8 * 8])     = c0;
      *reinterpret_cast<float4*>(&cwtL[r8][s8 * 8 + 4]) = c1;
    }
    __syncthreads();

    if (kc == oh)      { xs00 = preL[bh][63]; xs10 = preL[bh + 16][63]; }
    if (kc == oh + 16) { xs01 = preL[bh][63]; xs11 = preL[bh + 16][63]; }

#pragma unroll
    for (int kk = 0; kk < 64; kk += 4) {
      float4 p0 = *reinterpret_cast<const float4*>(&preL[bh][kk]);
      float4 p1 = *reinterpret_cast<const float4*>(&preL[bh + 16][kk]);
      float4 c0 = *reinterpret_cast<const float4*>(&cwtL[oh][kk]);
      float4 c1 = *reinterpret_cast<const float4*>(&cwtL[oh + 16][kk]);
      a00 = fmaf(p0.x, c0.x, a00); a00 = fmaf(p0.y, c0.y, a00);
      a00 = fmaf(p0.z, c0.z, a00); a00 = fmaf(p0.w, c0.w, a00);
      a01 = fmaf(p0.x, c1.x, a01); a01 = fmaf(p0.y, c1.y, a01);
      a01 = fmaf(p0.z, c1.z, a01); a01 = fmaf(p0.w, c1.w, a01);
      a10 = fmaf(p1.x, c0.x, a10); a10 = fmaf(p1.y, c0.y, a10);
      a10 = fmaf(p1.z, c0.z, a10); a10 = fmaf(p1.w, c0.w, a10);
      a11 = fmaf(p1.x, c1.x, a11); a11 = fmaf(p1.y, c1.y, a11);
      a11 = fmaf(p1.z, c1.z, a11); a11 = fmaf(p1.w, c1.w, a11);
    }
  }

  float cb0 = cb[g * 32 + oh], cb1 = cb[g * 32 + oh + 16];
  float v00 = a00 + xs00 + 64.f * cb0;
  float v01 = a01 + xs01 + 64.f * cb1;
  float v10 = a10 + xs10 + 64.f * cb0;
  float v11 = a11 + xs11 + 64.f * cb1;

  float sqA = v00 * v00 + v01 * v01;
  float sqB = v10 * v10 + v11 * v11;
#pragma unroll
  for (int m = 8; m >= 1; m >>= 1) {
    sqA += __shfl_xor(sqA, m, 16);
    sqB += __shfl_xor(sqB, m, 16);
  }
  float nA = sqrtf(sqA), nB = sqrtf(sqB);
  float cA = 1.f - 1.f / (expf(nA) + 1e-20f);
  float cB = 1.f - 1.f / (expf(nB) + 1e-20f);
  float iA = cA / (nA + 1e-20f), iB = cB / (nB + 1e-20f);

  size_t baseA = ((size_t)(b0 + bh) * NG + g) * ND;
  size_t baseB = ((size_t)(b0 + bh + 16) * NG + g) * ND;
  out[baseA + oh]      = v00 * iA;
  out[baseA + oh + 16] = v01 * iA;
  out[baseB + oh]      = v10 * iB;
  out[baseB + oh + 16] = v11 * iB;
}

// ---------------------------------------------------------------------------
extern "C" void kernel_launch(void* const* d_in, const int* in_sizes, int n_in,
                              void* d_out, int out_size, void* d_ws, size_t ws_size,
                              hipStream_t stream) {
  const float* x1 = (const float*)d_in[0];
  const float* x2 = (const float*)d_in[1];
  const float* x3 = (const float*)d_in[2];
  const float* W  = (const float*)d_in[3];
  const float* cw = (const float*)d_in[4];
  const float* cb = (const float*)d_in[5];
  float* out = (float*)d_out;

  float* ws   = (float*)d_ws;
  __half* uraw = (__half*)d_ws;
  float* pre  = ws + PRE_OFF;                       // overlays u2+u3 (halves)
  float* f    = ws + URAW_FLOATS;
  float* s1   = f + (size_t)NB * NC;
  float* kv   = s1 + (size_t)NB * NT;
  float* cwt  = kv + (size_t)NB * NT * NT;

  k_transform<<<3072, 256, 0, stream>>>(x1, x2, x3, W, uraw);
  k_zero<<<256, 256, 0, stream>>>(s1, (int)(NB * NT + NB * NT * NT));
  k_factors<<<512, 256, 0, stream>>>(uraw, f, s1);
  k_kv<<<1024, 256, 0, stream>>>(uraw, kv);
  k_cwt<<<2048, 64, 0, stream>>>(cw, cwt);
  k_pre<<<1024, 256, 0, stream>>>(uraw, f, kv, s1, pre);
  k_gemm<<<256, 256, 0, stream>>>(pre, cwt, cb, out);
}